// Round 10
// baseline (1466.213 us; speedup 1.0000x reference)
//
#include <hip/hip_runtime.h>
#include <hip/hip_bf16.h>

#define CCH   256
#define LPIX  35200
#define KSEL  3520
#define MCL   880
#define NBINS 16384
#define FMAXV 3.402823466e38f

typedef __bf16 bf16x8 __attribute__((ext_vector_type(8)));
typedef float  f32x4  __attribute__((ext_vector_type(4)));
typedef unsigned short ushort_t;

__device__ __forceinline__ void split3(float v, __bf16* h, __bf16* m, __bf16* l) {
    __bf16 a = (__bf16)v;
    float r = v - (float)a;
    __bf16 b = (__bf16)r;
    float r2 = r - (float)b;
    *h = a; *m = b; *l = (__bf16)r2;
}

// 6-term bf16x3 split: per-acc term order hh,hm,mh,hl,mm,lh (error ~2^-24).
__device__ constexpr int SA6[6] = {0, 0, 1, 0, 1, 2};
__device__ constexpr int SB6[6] = {0, 1, 0, 2, 1, 0};

// ---------------- W1 -> bf16x3 splits ----------------
__global__ void split_w1(const float* __restrict__ w1, __bf16* __restrict__ h,
                         __bf16* __restrict__ m, __bf16* __restrict__ l) {
    int i = blockIdx.x * 256 + threadIdx.x;
    split3(w1[i], &h[i], &m[i], &l[i]);
}

// ---------------- score MLP: MFMA bf16x3, ZERO-LDS / zero-barrier k-loop ----------------
// Each lane loads its own MFMA fragments directly from global (L2-hot):
//   B (x): 8 stride-LPIX scalars per (fj) -> wave covers 4 full 64B lines/inst; split3 in-reg.
//   A (w1 splits): contiguous bf16x8. No staging, no k-loop barriers -> waves desync and
//   keep the MFMA pipe fed continuously.
__global__ __launch_bounds__(256) void score_mfma(
    const float* __restrict__ x, const float* __restrict__ prio,
    const __bf16* __restrict__ w1h, const __bf16* __restrict__ w1m, const __bf16* __restrict__ w1l,
    const float* __restrict__ b1, const float* __restrict__ w2, const float* __restrict__ b2,
    float* __restrict__ weight) {
    int n = blockIdx.y;
    int l0 = blockIdx.x * 64;
    int tid = threadIdx.x, w = tid >> 6, lane = tid & 63;
    int lrow = lane & 15, kg = lane >> 4;
    __shared__ float spart[64][17];
    const float* xb = x + (size_t)n * CCH * LPIX + l0;
    f32x4 acc[4][4];
#pragma unroll
    for (int i = 0; i < 4; i++)
#pragma unroll
        for (int j = 0; j < 4; j++) acc[i][j] = (f32x4){0.f, 0.f, 0.f, 0.f};

#pragma unroll
    for (int k = 0; k < 8; k++) {
        const int c0 = k * 32 + kg * 8;
        bf16x8 bf[3][4];
        // load + split B fragments in fj pairs (bounds register pressure)
#pragma unroll
        for (int fp = 0; fp < 2; fp++) {
            float xv[2][8];
#pragma unroll
            for (int q = 0; q < 2; q++) {
                int pix = (fp * 2 + q) * 16 + lrow;
#pragma unroll
                for (int j = 0; j < 8; j++)
                    xv[q][j] = xb[(size_t)(c0 + j) * LPIX + pix];
            }
#pragma unroll
            for (int q = 0; q < 2; q++) {
                bf16x8 vh, vm, vl;
#pragma unroll
                for (int j = 0; j < 8; j++) {
                    __bf16 h, m, l;
                    split3(xv[q][j], &h, &m, &l);
                    vh[j] = h; vm[j] = m; vl[j] = l;
                }
                bf[0][fp * 2 + q] = vh;
                bf[1][fp * 2 + q] = vm;
                bf[2][fp * 2 + q] = vl;
            }
        }
        bf16x8 af[3][4];
#pragma unroll
        for (int fi = 0; fi < 4; fi++) {
            size_t ao = (size_t)(w * 64 + fi * 16 + lrow) * 256 + c0;
            af[0][fi] = *(const bf16x8*)&w1h[ao];
            af[1][fi] = *(const bf16x8*)&w1m[ao];
            af[2][fi] = *(const bf16x8*)&w1l[ao];
        }
        // term-major: 16 independent accs between writes to any single acc;
        // per-acc order t=0..5 (hh,hm,mh,hl,mm,lh) -> bit-identical numerics
#pragma unroll
        for (int t = 0; t < 6; t++) {
#pragma unroll
            for (int fi = 0; fi < 4; fi++) {
#pragma unroll
                for (int fj = 0; fj < 4; fj++) {
                    acc[fi][fj] = __builtin_amdgcn_mfma_f32_16x16x32_bf16(
                        af[SA6[t]][fi], bf[SB6[t]][fj], acc[fi][fj], 0, 0, 0);
                }
            }
        }
    }

    float ps[4] = {0.f, 0.f, 0.f, 0.f};
#pragma unroll
    for (int fi = 0; fi < 4; fi++) {
        int ob = w * 64 + fi * 16 + kg * 4;
        float4 b1v = *(const float4*)&b1[ob];
        float4 w2v = *(const float4*)&w2[ob];
        float b1a[4] = {b1v.x, b1v.y, b1v.z, b1v.w};
        float w2a[4] = {w2v.x, w2v.y, w2v.z, w2v.w};
#pragma unroll
        for (int r = 0; r < 4; r++)
#pragma unroll
            for (int fj = 0; fj < 4; fj++)
                ps[fj] += w2a[r] * fmaxf(acc[fi][fj][r] + b1a[r], 0.f);
    }
#pragma unroll
    for (int fj = 0; fj < 4; fj++) spart[fj * 16 + lrow][w * 4 + kg] = ps[fj];
    __syncthreads();
    if (tid < 64) {
        float s = 0.f;
#pragma unroll
        for (int r = 0; r < 16; r++) s += spart[tid][r];
        s += b2[0];
        float sg = 1.f / (1.f + expf(-s));
        weight[(size_t)n * LPIX + l0 + tid] = sg * prio[(size_t)n * LPIX + l0 + tid];
    }
}

// ---------------- histogram over weight ----------------
__global__ void hist_kernel(const float* __restrict__ weight, int* __restrict__ hist) {
    int n = blockIdx.y;
    int i = blockIdx.x * 256 + threadIdx.x;
    if (i >= LPIX) return;
    float w = weight[(size_t)n * LPIX + i];
    int b = (int)(w * (float)NBINS);
    b = min(max(b, 0), NBINS - 1);
    atomicAdd(&hist[(size_t)n * NBINS + b], 1);
}

__global__ __launch_bounds__(256) void thr_kernel(const int* __restrict__ hist, int* __restrict__ thrbin) {
    int n = blockIdx.x, t = threadIdx.x;
    const int CH = NBINS / 256;
    __shared__ int csum[256];
    __shared__ int bfound;
    int base = NBINS - (t + 1) * CH;
    int s = 0;
    for (int i = 0; i < CH; i++) s += hist[(size_t)n * NBINS + base + i];
    csum[t] = s;
    __syncthreads();
    if (t == 0) {
        int cum = 0, sel = 255;
        for (int u = 0; u < 256; u++) {
            cum += csum[u];
            csum[u] = cum;
            if (cum >= KSEL) { sel = u; break; }
        }
        bfound = sel;
    }
    __syncthreads();
    if (t == 0) {
        int u = bfound;
        int cumBefore = (u == 0) ? 0 : csum[u - 1];
        int base2 = NBINS - (u + 1) * CH;
        int cum = cumBefore, bsel = base2;
        for (int b = base2 + CH - 1; b >= base2; b--) {
            cum += hist[(size_t)n * NBINS + b];
            if (cum >= KSEL) { bsel = b; break; }
        }
        thrbin[n] = bsel;
    }
}

__global__ void cand_kernel(const float* __restrict__ weight, const int* __restrict__ thrbin,
                            float* __restrict__ candw, int* __restrict__ cidx, int* __restrict__ ccnt) {
    int n = blockIdx.y;
    int i = blockIdx.x * 256 + threadIdx.x;
    if (i >= LPIX) return;
    float w = weight[(size_t)n * LPIX + i];
    int b = (int)(w * (float)NBINS);
    b = min(max(b, 0), NBINS - 1);
    if (b >= thrbin[n]) {
        int p = atomicAdd(&ccnt[n], 1);
        candw[(size_t)n * LPIX + p] = w;
        cidx[(size_t)n * LPIX + p] = i;
    }
}

__global__ __launch_bounds__(256) void rank_kernel(const float* __restrict__ candw, const int* __restrict__ cidx,
                                                   const int* __restrict__ ccnt,
                                                   float* __restrict__ conf, int* __restrict__ sidx) {
    int n = blockIdx.y, i = blockIdx.x;
    int cnt = ccnt[n];
    if (i >= cnt) return;
    float wi = candw[(size_t)n * LPIX + i];
    int ii = cidx[(size_t)n * LPIX + i];
    int r = 0;
    for (int j = threadIdx.x; j < cnt; j += 256) {
        float wj = candw[(size_t)n * LPIX + j];
        int ij = cidx[(size_t)n * LPIX + j];
        if (wj > wi || (wj == wi && ij < ii)) r++;
    }
    __shared__ int red[256];
    red[threadIdx.x] = r;
    __syncthreads();
    for (int s = 128; s > 0; s >>= 1) {
        if (threadIdx.x < s) red[threadIdx.x] += red[threadIdx.x + s];
        __syncthreads();
    }
    if (threadIdx.x == 0) {
        int rank = red[0];
        if (rank < KSEL) {
            sidx[(size_t)n * KSEL + rank] = ii;
            conf[(size_t)n * KSEL + rank] = wi;
        }
    }
}

// ---------------- gather selected tokens + bf16x3 splits + sq + inverse map ----------------
__global__ __launch_bounds__(256) void gather_src(const float* __restrict__ x, const int* __restrict__ sidx,
                                                  const float* __restrict__ conf,
                                                  float* __restrict__ src,
                                                  __bf16* __restrict__ sh, __bf16* __restrict__ sm,
                                                  __bf16* __restrict__ sl,
                                                  float* __restrict__ sq, int* __restrict__ inv) {
    int n = blockIdx.y, k = blockIdx.x, c = threadIdx.x;
    int idx = sidx[(size_t)n * KSEL + k];
    float cf = conf[(size_t)n * KSEL + k];
    float v = x[((size_t)n * CCH + c) * LPIX + idx] * cf;
    size_t o = ((size_t)n * KSEL + k) * CCH + c;
    src[o] = v;
    __bf16 h, m, l;
    split3(v, &h, &m, &l);
    sh[o] = h; sm[o] = m; sl[o] = l;
    __shared__ float red[256];
    red[c] = v * v;
    __syncthreads();
    for (int s = 128; s > 0; s >>= 1) {
        if (c < s) red[c] += red[c + s];
        __syncthreads();
    }
    if (c == 0) {
        sq[(size_t)n * KSEL + k] = red[0];
        inv[(size_t)n * LPIX + idx] = k;
    }
}

// ---------------- dist GEMM: MFMA bf16x3, ZERO-LDS, triangular + mirror ----------------
// Both A and B fragments are contiguous bf16x8 rows of the split-src arrays
// (1.8MB/batch each -> L2-resident). Wave-wide each load = 16 fully-consumed
// 64B lines. No staging, no k-loop barriers.
__global__ __launch_bounds__(256) void dist_mfma(
    const __bf16* __restrict__ sh, const __bf16* __restrict__ sm, const __bf16* __restrict__ sl,
    const float* __restrict__ sq, float* __restrict__ dist, int n0) {
    int n = n0 + blockIdx.z;
    const size_t nbase = (size_t)n * KSEL * CCH;
    const float* sqn = sq + (size_t)n * KSEL;
    float* D = dist + (size_t)blockIdx.z * KSEL * KSEL;
    int b = blockIdx.x;
    int iT = (int)((sqrtf(8.f * (float)b + 1.f) - 1.f) * 0.5f);
    while ((iT + 1) * (iT + 2) / 2 <= b) iT++;
    while (iT * (iT + 1) / 2 > b) iT--;
    int jT = b - iT * (iT + 1) / 2;
    int bi = iT * 128, bj = jT * 128;
    int tid = threadIdx.x, w = tid >> 6, lane = tid & 63;
    int lrow = lane & 15, kg = lane >> 4;
    int wr = w >> 1, wc = w & 1;
    f32x4 acc[4][4];
#pragma unroll
    for (int i = 0; i < 4; i++)
#pragma unroll
        for (int j = 0; j < 4; j++) acc[i][j] = (f32x4){0.f, 0.f, 0.f, 0.f};

    // per-lane row offsets (clamped for the 3584>3520 tail; stores are guarded)
    size_t aoff[4], boff[4];
#pragma unroll
    for (int f = 0; f < 4; f++) {
        aoff[f] = nbase + (size_t)min(bi + wr * 64 + f * 16 + lrow, KSEL - 1) * CCH + kg * 8;
        boff[f] = nbase + (size_t)min(bj + wc * 64 + f * 16 + lrow, KSEL - 1) * CCH + kg * 8;
    }

#pragma unroll
    for (int k = 0; k < 8; k++) {
        const int c0 = k * 32;
        bf16x8 af[3][4], bf[3][4];
#pragma unroll
        for (int f = 0; f < 4; f++) {
            af[0][f] = *(const bf16x8*)&sh[aoff[f] + c0];
            af[1][f] = *(const bf16x8*)&sm[aoff[f] + c0];
            af[2][f] = *(const bf16x8*)&sl[aoff[f] + c0];
            bf[0][f] = *(const bf16x8*)&sh[boff[f] + c0];
            bf[1][f] = *(const bf16x8*)&sm[boff[f] + c0];
            bf[2][f] = *(const bf16x8*)&sl[boff[f] + c0];
        }
#pragma unroll
        for (int t = 0; t < 6; t++) {
#pragma unroll
            for (int fi = 0; fi < 4; fi++) {
#pragma unroll
                for (int fj = 0; fj < 4; fj++) {
                    acc[fi][fj] = __builtin_amdgcn_mfma_f32_16x16x32_bf16(
                        af[SA6[t]][fi], bf[SB6[t]][fj], acc[fi][fj], 0, 0, 0);
                }
            }
        }
    }
#pragma unroll
    for (int fi = 0; fi < 4; fi++) {
        int gi0 = bi + wr * 64 + fi * 16;
        if (gi0 >= KSEL) continue;
        float4 siv = *(const float4*)&sqn[gi0 + kg * 4];
        float sia[4] = {siv.x, siv.y, siv.z, siv.w};
#pragma unroll
        for (int fj = 0; fj < 4; fj++) {
            int gj0 = bj + wc * 64 + fj * 16;
            if (gj0 >= KSEL) continue;
            int gj = gj0 + lrow;
            float sj = sqn[gj];
            float dv[4];
#pragma unroll
            for (int r = 0; r < 4; r++) {
                int gi = gi0 + kg * 4 + r;
                dv[r] = fmaxf(sia[r] + sj - 2.f * acc[fi][fj][r], 0.f);
                D[(size_t)gi * KSEL + gj] = dv[r];
            }
            if (iT != jT) {
                *(float4*)&D[(size_t)gj * KSEL + gi0 + kg * 4] = *(float4*)dv;
            }
        }
    }
}

// ---------------- density: 4 rows/block, 64 lanes/row, float4 + in-place LDS merge ----------------
__global__ __launch_bounds__(256) void knn_density(const float* __restrict__ dist, float* __restrict__ density, int n0) {
    int n = n0 + blockIdx.y;
    int row = threadIdx.x >> 6;
    int lane = threadIdx.x & 63;
    int i = blockIdx.x * 4 + row;
    const float4* row4 = (const float4*)(dist + (size_t)blockIdx.y * KSEL * KSEL + (size_t)i * KSEL);
    float tt[10];
#pragma unroll
    for (int r = 0; r < 10; r++) tt[r] = FMAXV;
    for (int j4 = lane; j4 < KSEL / 4; j4 += 64) {
        float4 v4 = row4[j4];
        float vv[4] = {v4.x, v4.y, v4.z, v4.w};
#pragma unroll
        for (int q = 0; q < 4; q++) {
            float v = vv[q];
            if (v < tt[9]) {
                tt[9] = v;
#pragma unroll
                for (int r = 9; r > 0; r--) {
                    if (tt[r] < tt[r - 1]) { float tmp = tt[r - 1]; tt[r - 1] = tt[r]; tt[r] = tmp; }
                }
            }
        }
    }
    __shared__ float ls[4][64][10];
#pragma unroll
    for (int r = 0; r < 10; r++) ls[row][lane][r] = tt[r];
    __syncthreads();
    for (int s = 32; s >= 1; s >>= 1) {
        if (lane < s) {
            float out[10];
            int ia = 0, ib = 0;
#pragma unroll
            for (int r = 0; r < 10; r++) {
                float va = ls[row][lane][ia], vb = ls[row][lane + s][ib];
                if (va <= vb) { out[r] = va; ia++; } else { out[r] = vb; ib++; }
            }
#pragma unroll
            for (int r = 0; r < 10; r++) ls[row][lane][r] = out[r];
        }
        __syncthreads();
    }
    if (lane == 0) {
        float sum = 0.f;
#pragma unroll
        for (int r = 0; r < 10; r++) sum += ls[row][0][r];
        density[(size_t)n * KSEL + i] = expf(-sum * 0.1f) + (float)i * 1e-6f;
    }
}

// ---------------- delta & score (marker token -> +inf score) ----------------
__global__ __launch_bounds__(256) void delta_score(const float* __restrict__ dist, const float* __restrict__ density,
                                                   float* __restrict__ scoreb, int n0) {
    int n = n0 + blockIdx.y;
    int i = blockIdx.x;
    const float4* row = (const float4*)(dist + (size_t)blockIdx.y * KSEL * KSEL + (size_t)i * KSEL);
    const float* dn = density + (size_t)n * KSEL;
    const float4* dn4 = (const float4*)dn;
    float di = dn[i];
    float mn = FMAXV;
    for (int j4 = threadIdx.x; j4 < KSEL / 4; j4 += 256) {
        float4 d = dn4[j4];
        float4 v = row[j4];
        if (d.x > di) mn = fminf(mn, v.x);
        if (d.y > di) mn = fminf(mn, v.y);
        if (d.z > di) mn = fminf(mn, v.z);
        if (d.w > di) mn = fminf(mn, v.w);
    }
    __shared__ float red[256];
    red[threadIdx.x] = mn;
    __syncthreads();
    for (int s = 128; s > 0; s >>= 1) {
        if (threadIdx.x < s) red[threadIdx.x] = fminf(red[threadIdx.x], red[threadIdx.x + s]);
        __syncthreads();
    }
    if (threadIdx.x == 0) {
        float d = red[0];
        scoreb[(size_t)n * KSEL + i] = (d == FMAXV) ? FMAXV : d * di;
    }
}

__global__ __launch_bounds__(256) void center_rank(const float* __restrict__ scoreb, int* __restrict__ centers,
                                                   int* __restrict__ crank, int n0) {
    int n = n0 + blockIdx.y;
    int i = blockIdx.x;
    const float* sc = scoreb + (size_t)n * KSEL;
    float si = sc[i];
    int r = 0;
    for (int j = threadIdx.x; j < KSEL; j += 256) {
        float sj = sc[j];
        if (sj > si || (sj == si && j < i)) r++;
    }
    __shared__ int red[256];
    red[threadIdx.x] = r;
    __syncthreads();
    for (int s = 128; s > 0; s >>= 1) {
        if (threadIdx.x < s) red[threadIdx.x] += red[threadIdx.x + s];
        __syncthreads();
    }
    if (threadIdx.x == 0) {
        int rank = red[0];
        if (rank < MCL) {
            centers[(size_t)n * MCL + rank] = i;
            crank[(size_t)n * KSEL + i] = rank;
        }
    }
}

// ---------------- assign + fused merge_w ----------------
__global__ __launch_bounds__(256) void assign_kernel(const float* __restrict__ dist, const int* __restrict__ centers,
                                                     const int* __restrict__ crank, const float* __restrict__ conf,
                                                     int* __restrict__ clus, float* __restrict__ allw, int n0) {
    int n = n0 + blockIdx.y;
    const float* D = dist + (size_t)blockIdx.y * KSEL * KSEL;
    int kl = threadIdx.x & 63, mc = threadIdx.x >> 6;
    int k = blockIdx.x * 64 + kl;
    const int* ctr = centers + (size_t)n * MCL;
    float mn = FMAXV;
    int am = MCL;
    for (int m = mc * 220; m < (mc + 1) * 220; m++) {
        float v = D[(size_t)ctr[m] * KSEL + k];
        if (v < mn) { mn = v; am = m; }
    }
    __shared__ float mv[4][64];
    __shared__ int mi[4][64];
    mv[mc][kl] = mn;
    mi[mc][kl] = am;
    __syncthreads();
    if (mc == 0) {
        float best = mv[0][kl];
        int bm = mi[0][kl];
#pragma unroll
        for (int c = 1; c < 4; c++) {
            float v = mv[c][kl];
            int im = mi[c][kl];
            if (v < best || (v == best && im < bm)) { best = v; bm = im; }
        }
        int cr = crank[(size_t)n * KSEL + k];
        int cl = (cr >= 0) ? cr : bm;
        clus[(size_t)n * KSEL + k] = cl;
        atomicAdd(&allw[(size_t)n * MCL + cl], conf[(size_t)n * KSEL + k]);
    }
}

__global__ void merge_feat(const float* __restrict__ src, const float* __restrict__ conf,
                           const int* __restrict__ clus, float* __restrict__ merged, int n0) {
    int n = n0 + blockIdx.y;
    int k = blockIdx.x, c = threadIdx.x;
    float v = src[((size_t)n * KSEL + k) * CCH + c] * conf[(size_t)n * KSEL + k];
    atomicAdd(&merged[((size_t)n * MCL + clus[(size_t)n * KSEL + k]) * CCH + c], v);
}

__global__ void merged_div(float* __restrict__ merged, const float* __restrict__ allw) {
    int nm = blockIdx.x, c = threadIdx.x;
    merged[(size_t)nm * CCH + c] /= (allw[nm] + 1e-6f);
}

// ---------------- bev + fused ego heads: one pass over x ----------------
__global__ __launch_bounds__(256) void bev_kernel(const float* __restrict__ x, const int* __restrict__ inv,
                                                  const int* __restrict__ clus, const float* __restrict__ merged,
                                                  const int* __restrict__ reclen, int B,
                                                  const float* __restrict__ clsw, const float* __restrict__ clsb,
                                                  const float* __restrict__ regw, const float* __restrict__ regb,
                                                  float* __restrict__ out, float* __restrict__ psm,
                                                  float* __restrict__ rm) {
    int n = blockIdx.y;
    int l0 = (blockIdx.x * 256 + threadIdx.x) * 4;
    bool ego = false;
    int bego = 0;
    {
        int off = 0;
        for (int b = 0; b < B; b++) {
            if (n == off) { ego = true; bego = b; break; }
            off += reclen[b];
        }
    }
    __shared__ float ws[16][256];
    __shared__ float bs[16];
    if (ego) {
        for (int i = threadIdx.x; i < 16 * 256; i += 256) {
            int o = i >> 8, c = i & 255;
            ws[o][c] = (o < 2) ? clsw[o * 256 + c] : regw[(o - 2) * 256 + c];
        }
        if (threadIdx.x < 16) bs[threadIdx.x] = (threadIdx.x < 2) ? clsb[threadIdx.x] : regb[threadIdx.x - 2];
        __syncthreads();
    }
    if (l0 >= LPIX) return;
    size_t base = (size_t)n * CCH * LPIX + l0;
    if (ego) {
        float acc[16][4] = {};
        for (int c = 0; c < CCH; c++) {
            float4 v = *(const float4*)&x[base + (size_t)c * LPIX];
            *(float4*)&out[base + (size_t)c * LPIX] = v;
#pragma unroll
            for (int o = 0; o < 16; o++) {
                float wv = ws[o][c];
                acc[o][0] += wv * v.x; acc[o][1] += wv * v.y; acc[o][2] += wv * v.z; acc[o][3] += wv * v.w;
            }
        }
#pragma unroll
        for (int o = 0; o < 2; o++) {
            float4 r;
            r.x = acc[o][0] + bs[o]; r.y = acc[o][1] + bs[o]; r.z = acc[o][2] + bs[o]; r.w = acc[o][3] + bs[o];
            *(float4*)&psm[((size_t)bego * 2 + o) * LPIX + l0] = r;
        }
#pragma unroll
        for (int o = 0; o < 14; o++) {
            float4 r;
            float bb = bs[o + 2];
            r.x = acc[o + 2][0] + bb; r.y = acc[o + 2][1] + bb; r.z = acc[o + 2][2] + bb; r.w = acc[o + 2][3] + bb;
            *(float4*)&rm[((size_t)bego * 14 + o) * LPIX + l0] = r;
        }
    } else {
        const float* mr0; const float* mr1; const float* mr2; const float* mr3;
        {
            int t0 = inv[(size_t)n * LPIX + l0 + 0];
            int t1 = inv[(size_t)n * LPIX + l0 + 1];
            int t2 = inv[(size_t)n * LPIX + l0 + 2];
            int t3 = inv[(size_t)n * LPIX + l0 + 3];
            mr0 = (t0 >= 0) ? merged + ((size_t)n * MCL + clus[(size_t)n * KSEL + t0]) * CCH : nullptr;
            mr1 = (t1 >= 0) ? merged + ((size_t)n * MCL + clus[(size_t)n * KSEL + t1]) * CCH : nullptr;
            mr2 = (t2 >= 0) ? merged + ((size_t)n * MCL + clus[(size_t)n * KSEL + t2]) * CCH : nullptr;
            mr3 = (t3 >= 0) ? merged + ((size_t)n * MCL + clus[(size_t)n * KSEL + t3]) * CCH : nullptr;
        }
        for (int c = 0; c < CCH; c++) {
            float4 v;
            v.x = mr0 ? mr0[c] : 0.f;
            v.y = mr1 ? mr1[c] : 0.f;
            v.z = mr2 ? mr2[c] : 0.f;
            v.w = mr3 ? mr3[c] : 0.f;
            *(float4*)&out[base + (size_t)c * LPIX] = v;
        }
    }
}

extern "C" void kernel_launch(void* const* d_in, const int* in_sizes, int n_in,
                              void* d_out, int out_size, void* d_ws, size_t ws_size,
                              hipStream_t stream) {
    const float* x    = (const float*)d_in[0];
    const float* prio = (const float*)d_in[1];
    const float* w1   = (const float*)d_in[2];
    const float* b1   = (const float*)d_in[3];
    const float* w2   = (const float*)d_in[4];
    const float* b2   = (const float*)d_in[5];
    const float* clsw = (const float*)d_in[6];
    const float* clsb = (const float*)d_in[7];
    const float* regw = (const float*)d_in[8];
    const float* regb = (const float*)d_in[9];
    const int* reclen = (const int*)d_in[10];
    int N = in_sizes[0] / (CCH * LPIX);
    int B = in_sizes[10];
    float* out = (float*)d_out;

    char* p = (char*)d_ws;
    size_t off = 0;
    auto alloc = [&](size_t bytes) -> void* {
        void* r = p + off;
        off += (bytes + 255) & ~(size_t)255;
        return r;
    };
    __bf16* w1h    = (__bf16*)alloc(256 * 256 * 2);
    __bf16* w1m    = (__bf16*)alloc(256 * 256 * 2);
    __bf16* w1l    = (__bf16*)alloc(256 * 256 * 2);
    float* weight  = (float*)alloc((size_t)N * LPIX * 4);
    int*   hist    = (int*)alloc((size_t)N * NBINS * 4);
    int*   thrbin  = (int*)alloc((size_t)N * 4);
    int*   ccnt    = (int*)alloc((size_t)N * 4);
    float* candw   = (float*)alloc((size_t)N * LPIX * 4);
    int*   cidx    = (int*)alloc((size_t)N * LPIX * 4);
    int*   sidx    = (int*)alloc((size_t)N * KSEL * 4);
    float* conf    = (float*)alloc((size_t)N * KSEL * 4);
    float* src     = (float*)alloc((size_t)N * KSEL * CCH * 4);
    __bf16* srch   = (__bf16*)alloc((size_t)N * KSEL * CCH * 2);
    __bf16* srcm   = (__bf16*)alloc((size_t)N * KSEL * CCH * 2);
    __bf16* srcl   = (__bf16*)alloc((size_t)N * KSEL * CCH * 2);
    float* sq      = (float*)alloc((size_t)N * KSEL * 4);
    int*   inv     = (int*)alloc((size_t)N * LPIX * 4);
    float* density = (float*)alloc((size_t)N * KSEL * 4);
    float* scoreb  = (float*)alloc((size_t)N * KSEL * 4);
    int*   centers = (int*)alloc((size_t)N * MCL * 4);
    int*   crank   = (int*)alloc((size_t)N * KSEL * 4);
    int*   clus    = (int*)alloc((size_t)N * KSEL * 4);
    float* allw    = (float*)alloc((size_t)N * MCL * 4);
    float* merged  = (float*)alloc((size_t)N * MCL * CCH * 4);
    const size_t distB = (size_t)KSEL * KSEL * 4;
    size_t rem = (ws_size > off) ? (ws_size - off) : 0;
    int nd = (int)(rem / distB);
    if (nd < 1) nd = 1;
    if (nd > N) nd = N;
    if (nd > 4) nd = 4;
    float* dist = (float*)alloc(distB * nd);

    hipMemsetAsync(hist, 0, (size_t)N * NBINS * 4, stream);
    hipMemsetAsync(ccnt, 0, (size_t)N * 4, stream);
    hipMemsetAsync(inv, 0xFF, (size_t)N * LPIX * 4, stream);
    hipMemsetAsync(crank, 0xFF, (size_t)N * KSEL * 4, stream);
    hipMemsetAsync(allw, 0, (size_t)N * MCL * 4, stream);
    hipMemsetAsync(merged, 0, (size_t)N * MCL * CCH * 4, stream);

    split_w1<<<256, 256, 0, stream>>>(w1, w1h, w1m, w1l);
    score_mfma<<<dim3(LPIX / 64, N), 256, 0, stream>>>(x, prio, w1h, w1m, w1l, b1, w2, b2, weight);
    hist_kernel<<<dim3((LPIX + 255) / 256, N), 256, 0, stream>>>(weight, hist);
    thr_kernel<<<N, 256, 0, stream>>>(hist, thrbin);
    cand_kernel<<<dim3((LPIX + 255) / 256, N), 256, 0, stream>>>(weight, thrbin, candw, cidx, ccnt);
    rank_kernel<<<dim3(8192, N), 256, 0, stream>>>(candw, cidx, ccnt, conf, sidx);
    gather_src<<<dim3(KSEL, N), 256, 0, stream>>>(x, sidx, conf, src, srch, srcm, srcl, sq, inv);

    const int TI = (KSEL + 127) / 128;           // 28
    const int NT = TI * (TI + 1) / 2;            // 406 lower-triangle tiles
    for (int g = 0; g < N; g += nd) {
        int nb = (N - g < nd) ? (N - g) : nd;
        dist_mfma<<<dim3(NT, 1, nb), 256, 0, stream>>>(srch, srcm, srcl, sq, dist, g);
        knn_density<<<dim3(KSEL / 4, nb), 256, 0, stream>>>(dist, density, g);
        delta_score<<<dim3(KSEL, nb), 256, 0, stream>>>(dist, density, scoreb, g);
        center_rank<<<dim3(KSEL, nb), 256, 0, stream>>>(scoreb, centers, crank, g);
        assign_kernel<<<dim3(KSEL / 64, nb), 256, 0, stream>>>(dist, centers, crank, conf, clus, allw, g);
        merge_feat<<<dim3(KSEL, nb), 256, 0, stream>>>(src, conf, clus, merged, g);
    }
    merged_div<<<N * MCL, 256, 0, stream>>>(merged, allw);

    float* psm = out + (size_t)N * CCH * LPIX;
    float* rm  = psm + (size_t)B * 2 * LPIX;
    bev_kernel<<<dim3((LPIX / 4 + 255) / 256, N), 256, 0, stream>>>(
        x, inv, clus, merged, reclen, B, clsw, clsb, regw, regb, out, psm, rm);
}

// Round 11
// 1296.878 us; speedup vs baseline: 1.1306x; 1.1306x over previous
//
#include <hip/hip_runtime.h>
#include <hip/hip_bf16.h>

#define CCH   256
#define LPIX  35200
#define KSEL  3520
#define MCL   880
#define NBINS 16384
#define FMAXV 3.402823466e38f

typedef __bf16 bf16x8 __attribute__((ext_vector_type(8)));
typedef float  f32x4  __attribute__((ext_vector_type(4)));
typedef unsigned short ushort_t;

__device__ __forceinline__ void split3(float v, __bf16* h, __bf16* m, __bf16* l) {
    __bf16 a = (__bf16)v;
    float r = v - (float)a;
    __bf16 b = (__bf16)r;
    float r2 = r - (float)b;
    *h = a; *m = b; *l = (__bf16)r2;
}

// 6-term bf16x3 split: per-acc term order hh,hm,mh,hl,mm,lh (error ~2^-24).
// Emitted TERM-MAJOR across all independent accumulators.
__device__ constexpr int SA6[6] = {0, 0, 1, 0, 1, 2};
__device__ constexpr int SB6[6] = {0, 1, 0, 2, 1, 0};

// ---------------- W1 -> bf16x3 splits ----------------
__global__ void split_w1(const float* __restrict__ w1, __bf16* __restrict__ h,
                         __bf16* __restrict__ m, __bf16* __restrict__ l) {
    int i = blockIdx.x * 256 + threadIdx.x;
    split3(w1[i], &h[i], &m[i], &l[i]);
}

// ---------------- score MLP: MFMA bf16x3, pipelined LDS staging, term-major MFMA ----------------
// (round-8 best version; + fused histogram in epilogue)
__global__ __launch_bounds__(256) void score_mfma(
    const float* __restrict__ x, const float* __restrict__ prio,
    const __bf16* __restrict__ w1h, const __bf16* __restrict__ w1m, const __bf16* __restrict__ w1l,
    const float* __restrict__ b1, const float* __restrict__ w2, const float* __restrict__ b2,
    float* __restrict__ weight, int* __restrict__ hist) {
    int n = blockIdx.y;
    int l0 = blockIdx.x * 64;
    int tid = threadIdx.x, w = tid >> 6, lane = tid & 63;
    int lrow = lane & 15, kg = lane >> 4;
    __shared__ __align__(16) __bf16 Xs[2][3][64][40];
    __shared__ float spart[64][17];
    const float* xb = x + (size_t)n * CCH * LPIX;
    f32x4 acc[4][4];
#pragma unroll
    for (int i = 0; i < 4; i++)
#pragma unroll
        for (int j = 0; j < 4; j++) acc[i][j] = (f32x4){0.f, 0.f, 0.f, 0.f};

    int sl = tid & 63;   // pixel within tile
    int cg = tid >> 6;   // channel octet (8 channels each, 32 per k-step)

    auto loadx = [&](int k, float* dst) {
        int c0 = k * 32 + cg * 8;
#pragma unroll
        for (int j = 0; j < 8; j++)
            dst[j] = xb[(size_t)(c0 + j) * LPIX + l0 + sl];
    };
    auto loadw = [&](int k, bf16x8* dst) {
#pragma unroll
        for (int fi = 0; fi < 4; fi++) {
            size_t ao = (size_t)(w * 64 + fi * 16 + lrow) * 256 + k * 32 + kg * 8;
            dst[fi * 3 + 0] = *(const bf16x8*)&w1h[ao];
            dst[fi * 3 + 1] = *(const bf16x8*)&w1m[ao];
            dst[fi * 3 + 2] = *(const bf16x8*)&w1l[ao];
        }
    };
    auto stage = [&](int buf, const float* v) {
        bf16x8 vh, vm, vl;
#pragma unroll
        for (int j = 0; j < 8; j++) {
            __bf16 h, m, l;
            split3(v[j], &h, &m, &l);
            vh[j] = h; vm[j] = m; vl[j] = l;
        }
        *(bf16x8*)&Xs[buf][0][sl][cg * 8] = vh;
        *(bf16x8*)&Xs[buf][1][sl][cg * 8] = vm;
        *(bf16x8*)&Xs[buf][2][sl][cg * 8] = vl;
    };

    float pf[2][8];
    bf16x8 wfr[2][12];
    loadx(0, pf[0]);
    loadw(0, wfr[0]);
    stage(0, pf[0]);
    loadx(1, pf[1]);
    __syncthreads();

#pragma unroll
    for (int k = 0; k < 8; k++) {
        const int buf = k & 1;
        bf16x8 bf[3][4];
#pragma unroll
        for (int fj = 0; fj < 4; fj++) {
            bf[0][fj] = *(const bf16x8*)&Xs[buf][0][fj * 16 + lrow][kg * 8];
            bf[1][fj] = *(const bf16x8*)&Xs[buf][1][fj * 16 + lrow][kg * 8];
            bf[2][fj] = *(const bf16x8*)&Xs[buf][2][fj * 16 + lrow][kg * 8];
        }
        if (k < 7) loadw(k + 1, wfr[buf ^ 1]);   // W1 for next step (hides under MFMA)
        if (k < 6) loadx(k + 2, pf[buf]);        // x tile k+2
        if (k < 7) stage(buf ^ 1, pf[buf ^ 1]);  // split+write tile k+1 (conflict-free b128)
        // term-major: 16 independent accs between writes to any single acc
#pragma unroll
        for (int t = 0; t < 6; t++) {
#pragma unroll
            for (int fi = 0; fi < 4; fi++) {
#pragma unroll
                for (int fj = 0; fj < 4; fj++) {
                    acc[fi][fj] = __builtin_amdgcn_mfma_f32_16x16x32_bf16(
                        wfr[buf][fi * 3 + SA6[t]], bf[SB6[t]][fj], acc[fi][fj], 0, 0, 0);
                }
            }
        }
        __syncthreads();
    }

    float ps[4] = {0.f, 0.f, 0.f, 0.f};
#pragma unroll
    for (int fi = 0; fi < 4; fi++) {
        int ob = w * 64 + fi * 16 + kg * 4;
        float4 b1v = *(const float4*)&b1[ob];
        float4 w2v = *(const float4*)&w2[ob];
        float b1a[4] = {b1v.x, b1v.y, b1v.z, b1v.w};
        float w2a[4] = {w2v.x, w2v.y, w2v.z, w2v.w};
#pragma unroll
        for (int r = 0; r < 4; r++)
#pragma unroll
            for (int fj = 0; fj < 4; fj++)
                ps[fj] += w2a[r] * fmaxf(acc[fi][fj][r] + b1a[r], 0.f);
    }
#pragma unroll
    for (int fj = 0; fj < 4; fj++) spart[fj * 16 + lrow][w * 4 + kg] = ps[fj];
    __syncthreads();
    if (tid < 64) {
        float s = 0.f;
#pragma unroll
        for (int r = 0; r < 16; r++) s += spart[tid][r];
        s += b2[0];
        float sg = 1.f / (1.f + expf(-s));
        float wv = sg * prio[(size_t)n * LPIX + l0 + tid];
        weight[(size_t)n * LPIX + l0 + tid] = wv;
        // fused histogram
        int b = (int)(wv * (float)NBINS);
        b = min(max(b, 0), NBINS - 1);
        atomicAdd(&hist[(size_t)n * NBINS + b], 1);
    }
}

__global__ __launch_bounds__(256) void thr_kernel(const int* __restrict__ hist, int* __restrict__ thrbin) {
    int n = blockIdx.x, t = threadIdx.x;
    const int CH = NBINS / 256;
    __shared__ int csum[256];
    __shared__ int bfound;
    int base = NBINS - (t + 1) * CH;
    int s = 0;
    for (int i = 0; i < CH; i++) s += hist[(size_t)n * NBINS + base + i];
    csum[t] = s;
    __syncthreads();
    if (t == 0) {
        int cum = 0, sel = 255;
        for (int u = 0; u < 256; u++) {
            cum += csum[u];
            csum[u] = cum;
            if (cum >= KSEL) { sel = u; break; }
        }
        bfound = sel;
    }
    __syncthreads();
    if (t == 0) {
        int u = bfound;
        int cumBefore = (u == 0) ? 0 : csum[u - 1];
        int base2 = NBINS - (u + 1) * CH;
        int cum = cumBefore, bsel = base2;
        for (int b = base2 + CH - 1; b >= base2; b--) {
            cum += hist[(size_t)n * NBINS + b];
            if (cum >= KSEL) { bsel = b; break; }
        }
        thrbin[n] = bsel;
    }
}

__global__ void cand_kernel(const float* __restrict__ weight, const int* __restrict__ thrbin,
                            float* __restrict__ candw, int* __restrict__ cidx, int* __restrict__ ccnt) {
    int n = blockIdx.y;
    int i = blockIdx.x * 256 + threadIdx.x;
    if (i >= LPIX) return;
    float w = weight[(size_t)n * LPIX + i];
    int b = (int)(w * (float)NBINS);
    b = min(max(b, 0), NBINS - 1);
    if (b >= thrbin[n]) {
        int p = atomicAdd(&ccnt[n], 1);
        candw[(size_t)n * LPIX + p] = w;
        cidx[(size_t)n * LPIX + p] = i;
    }
}

__global__ __launch_bounds__(256) void rank_kernel(const float* __restrict__ candw, const int* __restrict__ cidx,
                                                   const int* __restrict__ ccnt,
                                                   float* __restrict__ conf, int* __restrict__ sidx) {
    int n = blockIdx.y, i = blockIdx.x;
    int cnt = ccnt[n];
    if (i >= cnt) return;
    float wi = candw[(size_t)n * LPIX + i];
    int ii = cidx[(size_t)n * LPIX + i];
    int r = 0;
    for (int j = threadIdx.x; j < cnt; j += 256) {
        float wj = candw[(size_t)n * LPIX + j];
        int ij = cidx[(size_t)n * LPIX + j];
        if (wj > wi || (wj == wi && ij < ii)) r++;
    }
    __shared__ int red[256];
    red[threadIdx.x] = r;
    __syncthreads();
    for (int s = 128; s > 0; s >>= 1) {
        if (threadIdx.x < s) red[threadIdx.x] += red[threadIdx.x + s];
        __syncthreads();
    }
    if (threadIdx.x == 0) {
        int rank = red[0];
        if (rank < KSEL) {
            sidx[(size_t)n * KSEL + rank] = ii;
            conf[(size_t)n * KSEL + rank] = wi;
        }
    }
}

// ---------------- gather selected tokens + bf16x3 splits + sq + inverse map ----------------
__global__ __launch_bounds__(256) void gather_src(const float* __restrict__ x, const int* __restrict__ sidx,
                                                  const float* __restrict__ conf,
                                                  float* __restrict__ src,
                                                  __bf16* __restrict__ sh, __bf16* __restrict__ sm,
                                                  __bf16* __restrict__ sl,
                                                  float* __restrict__ sq, int* __restrict__ inv) {
    int n = blockIdx.y, k = blockIdx.x, c = threadIdx.x;
    int idx = sidx[(size_t)n * KSEL + k];
    float cf = conf[(size_t)n * KSEL + k];
    float v = x[((size_t)n * CCH + c) * LPIX + idx] * cf;
    size_t o = ((size_t)n * KSEL + k) * CCH + c;
    src[o] = v;
    __bf16 h, m, l;
    split3(v, &h, &m, &l);
    sh[o] = h; sm[o] = m; sl[o] = l;
    __shared__ float red[256];
    red[c] = v * v;
    __syncthreads();
    for (int s = 128; s > 0; s >>= 1) {
        if (c < s) red[c] += red[c + s];
        __syncthreads();
    }
    if (c == 0) {
        sq[(size_t)n * KSEL + k] = red[0];
        inv[(size_t)n * LPIX + idx] = k;
    }
}

// ---------------- dist GEMM: MFMA bf16x3, triangular + mirror, term-major (round-8 best) ----------------
__global__ __launch_bounds__(256) void dist_mfma(
    const __bf16* __restrict__ sh, const __bf16* __restrict__ sm, const __bf16* __restrict__ sl,
    const float* __restrict__ sq, float* __restrict__ dist, int n0) {
    int n = n0 + blockIdx.z;
    const size_t nbase = (size_t)n * KSEL * CCH;
    const float* sqn = sq + (size_t)n * KSEL;
    float* D = dist + (size_t)blockIdx.z * KSEL * KSEL;
    int b = blockIdx.x;
    int iT = (int)((sqrtf(8.f * (float)b + 1.f) - 1.f) * 0.5f);
    while ((iT + 1) * (iT + 2) / 2 <= b) iT++;
    while (iT * (iT + 1) / 2 > b) iT--;
    int jT = b - iT * (iT + 1) / 2;
    int bi = iT * 128, bj = jT * 128;
    __shared__ __align__(16) __bf16 As[3][128][40], Bs[3][128][40];
    int tid = threadIdx.x, w = tid >> 6, lane = tid & 63;
    int lrow = lane & 15, kg = lane >> 4;
    int wr = w >> 1, wc = w & 1;
    f32x4 acc[4][4];
#pragma unroll
    for (int i = 0; i < 4; i++)
#pragma unroll
        for (int j = 0; j < 4; j++) acc[i][j] = (f32x4){0.f, 0.f, 0.f, 0.f};

    int sr = tid & 127, g2 = tid >> 7;
    size_t ra = nbase + (size_t)min(bi + sr, KSEL - 1) * CCH;
    size_t rb = nbase + (size_t)min(bj + sr, KSEL - 1) * CCH;

    bf16x8 rA[3][2], rB[3][2];
#pragma unroll
    for (int s2 = 0; s2 < 2; s2++) {
        int cg = s2 * 2 + g2;
        rA[0][s2] = *(const bf16x8*)&sh[ra + cg * 8];
        rA[1][s2] = *(const bf16x8*)&sm[ra + cg * 8];
        rA[2][s2] = *(const bf16x8*)&sl[ra + cg * 8];
        rB[0][s2] = *(const bf16x8*)&sh[rb + cg * 8];
        rB[1][s2] = *(const bf16x8*)&sm[rb + cg * 8];
        rB[2][s2] = *(const bf16x8*)&sl[rb + cg * 8];
    }
    for (int c0 = 0; c0 < 256; c0 += 32) {
        __syncthreads();
#pragma unroll
        for (int s2 = 0; s2 < 2; s2++) {
            int cg = s2 * 2 + g2;
            *(bf16x8*)&As[0][sr][cg * 8] = rA[0][s2];
            *(bf16x8*)&As[1][sr][cg * 8] = rA[1][s2];
            *(bf16x8*)&As[2][sr][cg * 8] = rA[2][s2];
            *(bf16x8*)&Bs[0][sr][cg * 8] = rB[0][s2];
            *(bf16x8*)&Bs[1][sr][cg * 8] = rB[1][s2];
            *(bf16x8*)&Bs[2][sr][cg * 8] = rB[2][s2];
        }
        __syncthreads();
        if (c0 < 224) {
            int c1 = c0 + 32;
#pragma unroll
            for (int s2 = 0; s2 < 2; s2++) {
                int cg = s2 * 2 + g2;
                rA[0][s2] = *(const bf16x8*)&sh[ra + c1 + cg * 8];
                rA[1][s2] = *(const bf16x8*)&sm[ra + c1 + cg * 8];
                rA[2][s2] = *(const bf16x8*)&sl[ra + c1 + cg * 8];
                rB[0][s2] = *(const bf16x8*)&sh[rb + c1 + cg * 8];
                rB[1][s2] = *(const bf16x8*)&sm[rb + c1 + cg * 8];
                rB[2][s2] = *(const bf16x8*)&sl[rb + c1 + cg * 8];
            }
        }
        bf16x8 af[3][4], bf[3][4];
#pragma unroll
        for (int fj = 0; fj < 4; fj++) {
            int brow = wc * 64 + fj * 16 + lrow;
            bf[0][fj] = *(const bf16x8*)&Bs[0][brow][kg * 8];
            bf[1][fj] = *(const bf16x8*)&Bs[1][brow][kg * 8];
            bf[2][fj] = *(const bf16x8*)&Bs[2][brow][kg * 8];
        }
#pragma unroll
        for (int fi = 0; fi < 4; fi++) {
            int arow = wr * 64 + fi * 16 + lrow;
            af[0][fi] = *(const bf16x8*)&As[0][arow][kg * 8];
            af[1][fi] = *(const bf16x8*)&As[1][arow][kg * 8];
            af[2][fi] = *(const bf16x8*)&As[2][arow][kg * 8];
        }
#pragma unroll
        for (int t = 0; t < 6; t++) {
#pragma unroll
            for (int fi = 0; fi < 4; fi++) {
#pragma unroll
                for (int fj = 0; fj < 4; fj++) {
                    acc[fi][fj] = __builtin_amdgcn_mfma_f32_16x16x32_bf16(
                        af[SA6[t]][fi], bf[SB6[t]][fj], acc[fi][fj], 0, 0, 0);
                }
            }
        }
    }
#pragma unroll
    for (int fi = 0; fi < 4; fi++) {
        int gi0 = bi + wr * 64 + fi * 16;
        if (gi0 >= KSEL) continue;
        float4 siv = *(const float4*)&sqn[gi0 + kg * 4];
        float sia[4] = {siv.x, siv.y, siv.z, siv.w};
#pragma unroll
        for (int fj = 0; fj < 4; fj++) {
            int gj0 = bj + wc * 64 + fj * 16;
            if (gj0 >= KSEL) continue;
            int gj = gj0 + lrow;
            float sj = sqn[gj];
            float dv[4];
#pragma unroll
            for (int r = 0; r < 4; r++) {
                int gi = gi0 + kg * 4 + r;
                dv[r] = fmaxf(sia[r] + sj - 2.f * acc[fi][fj][r], 0.f);
                D[(size_t)gi * KSEL + gj] = dv[r];
            }
            if (iT != jT) {
                *(float4*)&D[(size_t)gj * KSEL + gi0 + kg * 4] = *(float4*)dv;
            }
        }
    }
}

// ---------------- density: 4 rows/block, 64 lanes/row, float4 + in-place LDS merge ----------------
__global__ __launch_bounds__(256) void knn_density(const float* __restrict__ dist, float* __restrict__ density, int n0) {
    int n = n0 + blockIdx.y;
    int row = threadIdx.x >> 6;
    int lane = threadIdx.x & 63;
    int i = blockIdx.x * 4 + row;
    const float4* row4 = (const float4*)(dist + (size_t)blockIdx.y * KSEL * KSEL + (size_t)i * KSEL);
    float tt[10];
#pragma unroll
    for (int r = 0; r < 10; r++) tt[r] = FMAXV;
    for (int j4 = lane; j4 < KSEL / 4; j4 += 64) {
        float4 v4 = row4[j4];
        float vv[4] = {v4.x, v4.y, v4.z, v4.w};
#pragma unroll
        for (int q = 0; q < 4; q++) {
            float v = vv[q];
            if (v < tt[9]) {
                tt[9] = v;
#pragma unroll
                for (int r = 9; r > 0; r--) {
                    if (tt[r] < tt[r - 1]) { float tmp = tt[r - 1]; tt[r - 1] = tt[r]; tt[r] = tmp; }
                }
            }
        }
    }
    __shared__ float ls[4][64][10];
#pragma unroll
    for (int r = 0; r < 10; r++) ls[row][lane][r] = tt[r];
    __syncthreads();
    for (int s = 32; s >= 1; s >>= 1) {
        if (lane < s) {
            float out[10];
            int ia = 0, ib = 0;
#pragma unroll
            for (int r = 0; r < 10; r++) {
                float va = ls[row][lane][ia], vb = ls[row][lane + s][ib];
                if (va <= vb) { out[r] = va; ia++; } else { out[r] = vb; ib++; }
            }
#pragma unroll
            for (int r = 0; r < 10; r++) ls[row][lane][r] = out[r];
        }
        __syncthreads();
    }
    if (lane == 0) {
        float sum = 0.f;
#pragma unroll
        for (int r = 0; r < 10; r++) sum += ls[row][0][r];
        density[(size_t)n * KSEL + i] = expf(-sum * 0.1f) + (float)i * 1e-6f;
    }
}

// ---------------- delta & score (marker token -> +inf score) ----------------
__global__ __launch_bounds__(256) void delta_score(const float* __restrict__ dist, const float* __restrict__ density,
                                                   float* __restrict__ scoreb, int n0) {
    int n = n0 + blockIdx.y;
    int i = blockIdx.x;
    const float4* row = (const float4*)(dist + (size_t)blockIdx.y * KSEL * KSEL + (size_t)i * KSEL);
    const float* dn = density + (size_t)n * KSEL;
    const float4* dn4 = (const float4*)dn;
    float di = dn[i];
    float mn = FMAXV;
    for (int j4 = threadIdx.x; j4 < KSEL / 4; j4 += 256) {
        float4 d = dn4[j4];
        float4 v = row[j4];
        if (d.x > di) mn = fminf(mn, v.x);
        if (d.y > di) mn = fminf(mn, v.y);
        if (d.z > di) mn = fminf(mn, v.z);
        if (d.w > di) mn = fminf(mn, v.w);
    }
    __shared__ float red[256];
    red[threadIdx.x] = mn;
    __syncthreads();
    for (int s = 128; s > 0; s >>= 1) {
        if (threadIdx.x < s) red[threadIdx.x] = fminf(red[threadIdx.x], red[threadIdx.x + s]);
        __syncthreads();
    }
    if (threadIdx.x == 0) {
        float d = red[0];
        scoreb[(size_t)n * KSEL + i] = (d == FMAXV) ? FMAXV : d * di;
    }
}

__global__ __launch_bounds__(256) void center_rank(const float* __restrict__ scoreb, int* __restrict__ centers,
                                                   int* __restrict__ crank, int n0) {
    int n = n0 + blockIdx.y;
    int i = blockIdx.x;
    const float* sc = scoreb + (size_t)n * KSEL;
    float si = sc[i];
    int r = 0;
    for (int j = threadIdx.x; j < KSEL; j += 256) {
        float sj = sc[j];
        if (sj > si || (sj == si && j < i)) r++;
    }
    __shared__ int red[256];
    red[threadIdx.x] = r;
    __syncthreads();
    for (int s = 128; s > 0; s >>= 1) {
        if (threadIdx.x < s) red[threadIdx.x] += red[threadIdx.x + s];
        __syncthreads();
    }
    if (threadIdx.x == 0) {
        int rank = red[0];
        if (rank < MCL) {
            centers[(size_t)n * MCL + rank] = i;
            crank[(size_t)n * KSEL + i] = rank;
        }
    }
}

// ---------------- assign + fused merge_w ----------------
__global__ __launch_bounds__(256) void assign_kernel(const float* __restrict__ dist, const int* __restrict__ centers,
                                                     const int* __restrict__ crank, const float* __restrict__ conf,
                                                     int* __restrict__ clus, float* __restrict__ allw, int n0) {
    int n = n0 + blockIdx.y;
    const float* D = dist + (size_t)blockIdx.y * KSEL * KSEL;
    int kl = threadIdx.x & 63, mc = threadIdx.x >> 6;
    int k = blockIdx.x * 64 + kl;
    const int* ctr = centers + (size_t)n * MCL;
    float mn = FMAXV;
    int am = MCL;
    for (int m = mc * 220; m < (mc + 1) * 220; m++) {
        float v = D[(size_t)ctr[m] * KSEL + k];
        if (v < mn) { mn = v; am = m; }
    }
    __shared__ float mv[4][64];
    __shared__ int mi[4][64];
    mv[mc][kl] = mn;
    mi[mc][kl] = am;
    __syncthreads();
    if (mc == 0) {
        float best = mv[0][kl];
        int bm = mi[0][kl];
#pragma unroll
        for (int c = 1; c < 4; c++) {
            float v = mv[c][kl];
            int im = mi[c][kl];
            if (v < best || (v == best && im < bm)) { best = v; bm = im; }
        }
        int cr = crank[(size_t)n * KSEL + k];
        int cl = (cr >= 0) ? cr : bm;
        clus[(size_t)n * KSEL + k] = cl;
        atomicAdd(&allw[(size_t)n * MCL + cl], conf[(size_t)n * KSEL + k]);
    }
}

__global__ void merge_feat(const float* __restrict__ src, const float* __restrict__ conf,
                           const int* __restrict__ clus, float* __restrict__ merged, int n0) {
    int n = n0 + blockIdx.y;
    int k = blockIdx.x, c = threadIdx.x;
    float v = src[((size_t)n * KSEL + k) * CCH + c] * conf[(size_t)n * KSEL + k];
    atomicAdd(&merged[((size_t)n * MCL + clus[(size_t)n * KSEL + k]) * CCH + c], v);
}

__global__ void merged_div(float* __restrict__ merged, const float* __restrict__ allw) {
    int nm = blockIdx.x, c = threadIdx.x;
    merged[(size_t)nm * CCH + c] /= (allw[nm] + 1e-6f);
}

// ---------------- bev + fused ego heads: one pass over x ----------------
__global__ __launch_bounds__(256) void bev_kernel(const float* __restrict__ x, const int* __restrict__ inv,
                                                  const int* __restrict__ clus, const float* __restrict__ merged,
                                                  const int* __restrict__ reclen, int B,
                                                  const float* __restrict__ clsw, const float* __restrict__ clsb,
                                                  const float* __restrict__ regw, const float* __restrict__ regb,
                                                  float* __restrict__ out, float* __restrict__ psm,
                                                  float* __restrict__ rm) {
    int n = blockIdx.y;
    int l0 = (blockIdx.x * 256 + threadIdx.x) * 4;
    bool ego = false;
    int bego = 0;
    {
        int off = 0;
        for (int b = 0; b < B; b++) {
            if (n == off) { ego = true; bego = b; break; }
            off += reclen[b];
        }
    }
    __shared__ float ws[16][256];
    __shared__ float bs[16];
    if (ego) {
        for (int i = threadIdx.x; i < 16 * 256; i += 256) {
            int o = i >> 8, c = i & 255;
            ws[o][c] = (o < 2) ? clsw[o * 256 + c] : regw[(o - 2) * 256 + c];
        }
        if (threadIdx.x < 16) bs[threadIdx.x] = (threadIdx.x < 2) ? clsb[threadIdx.x] : regb[threadIdx.x - 2];
        __syncthreads();
    }
    if (l0 >= LPIX) return;
    size_t base = (size_t)n * CCH * LPIX + l0;
    if (ego) {
        float acc[16][4] = {};
        for (int c = 0; c < CCH; c++) {
            float4 v = *(const float4*)&x[base + (size_t)c * LPIX];
            *(float4*)&out[base + (size_t)c * LPIX] = v;
#pragma unroll
            for (int o = 0; o < 16; o++) {
                float wv = ws[o][c];
                acc[o][0] += wv * v.x; acc[o][1] += wv * v.y; acc[o][2] += wv * v.z; acc[o][3] += wv * v.w;
            }
        }
#pragma unroll
        for (int o = 0; o < 2; o++) {
            float4 r;
            r.x = acc[o][0] + bs[o]; r.y = acc[o][1] + bs[o]; r.z = acc[o][2] + bs[o]; r.w = acc[o][3] + bs[o];
            *(float4*)&psm[((size_t)bego * 2 + o) * LPIX + l0] = r;
        }
#pragma unroll
        for (int o = 0; o < 14; o++) {
            float4 r;
            float bb = bs[o + 2];
            r.x = acc[o + 2][0] + bb; r.y = acc[o + 2][1] + bb; r.z = acc[o + 2][2] + bb; r.w = acc[o + 2][3] + bb;
            *(float4*)&rm[((size_t)bego * 14 + o) * LPIX + l0] = r;
        }
    } else {
        const float* mr0; const float* mr1; const float* mr2; const float* mr3;
        {
            int t0 = inv[(size_t)n * LPIX + l0 + 0];
            int t1 = inv[(size_t)n * LPIX + l0 + 1];
            int t2 = inv[(size_t)n * LPIX + l0 + 2];
            int t3 = inv[(size_t)n * LPIX + l0 + 3];
            mr0 = (t0 >= 0) ? merged + ((size_t)n * MCL + clus[(size_t)n * KSEL + t0]) * CCH : nullptr;
            mr1 = (t1 >= 0) ? merged + ((size_t)n * MCL + clus[(size_t)n * KSEL + t1]) * CCH : nullptr;
            mr2 = (t2 >= 0) ? merged + ((size_t)n * MCL + clus[(size_t)n * KSEL + t2]) * CCH : nullptr;
            mr3 = (t3 >= 0) ? merged + ((size_t)n * MCL + clus[(size_t)n * KSEL + t3]) * CCH : nullptr;
        }
        for (int c = 0; c < CCH; c++) {
            float4 v;
            v.x = mr0 ? mr0[c] : 0.f;
            v.y = mr1 ? mr1[c] : 0.f;
            v.z = mr2 ? mr2[c] : 0.f;
            v.w = mr3 ? mr3[c] : 0.f;
            *(float4*)&out[base + (size_t)c * LPIX] = v;
        }
    }
}

extern "C" void kernel_launch(void* const* d_in, const int* in_sizes, int n_in,
                              void* d_out, int out_size, void* d_ws, size_t ws_size,
                              hipStream_t stream) {
    const float* x    = (const float*)d_in[0];
    const float* prio = (const float*)d_in[1];
    const float* w1   = (const float*)d_in[2];
    const float* b1   = (const float*)d_in[3];
    const float* w2   = (const float*)d_in[4];
    const float* b2   = (const float*)d_in[5];
    const float* clsw = (const float*)d_in[6];
    const float* clsb = (const float*)d_in[7];
    const float* regw = (const float*)d_in[8];
    const float* regb = (const float*)d_in[9];
    const int* reclen = (const int*)d_in[10];
    int N = in_sizes[0] / (CCH * LPIX);
    int B = in_sizes[10];
    float* out = (float*)d_out;

    char* p = (char*)d_ws;
    size_t off = 0;
    auto alloc = [&](size_t bytes) -> void* {
        void* r = p + off;
        off += (bytes + 255) & ~(size_t)255;
        return r;
    };
    __bf16* w1h    = (__bf16*)alloc(256 * 256 * 2);
    __bf16* w1m    = (__bf16*)alloc(256 * 256 * 2);
    __bf16* w1l    = (__bf16*)alloc(256 * 256 * 2);
    float* weight  = (float*)alloc((size_t)N * LPIX * 4);
    int*   hist    = (int*)alloc((size_t)N * NBINS * 4);
    int*   thrbin  = (int*)alloc((size_t)N * 4);
    int*   ccnt    = (int*)alloc((size_t)N * 4);
    float* candw   = (float*)alloc((size_t)N * LPIX * 4);
    int*   cidx    = (int*)alloc((size_t)N * LPIX * 4);
    int*   sidx    = (int*)alloc((size_t)N * KSEL * 4);
    float* conf    = (float*)alloc((size_t)N * KSEL * 4);
    float* src     = (float*)alloc((size_t)N * KSEL * CCH * 4);
    __bf16* srch   = (__bf16*)alloc((size_t)N * KSEL * CCH * 2);
    __bf16* srcm   = (__bf16*)alloc((size_t)N * KSEL * CCH * 2);
    __bf16* srcl   = (__bf16*)alloc((size_t)N * KSEL * CCH * 2);
    float* sq      = (float*)alloc((size_t)N * KSEL * 4);
    int*   inv     = (int*)alloc((size_t)N * LPIX * 4);
    float* density = (float*)alloc((size_t)N * KSEL * 4);
    float* scoreb  = (float*)alloc((size_t)N * KSEL * 4);
    int*   centers = (int*)alloc((size_t)N * MCL * 4);
    int*   crank   = (int*)alloc((size_t)N * KSEL * 4);
    int*   clus    = (int*)alloc((size_t)N * KSEL * 4);
    float* allw    = (float*)alloc((size_t)N * MCL * 4);
    float* merged  = (float*)alloc((size_t)N * MCL * CCH * 4);
    const size_t distB = (size_t)KSEL * KSEL * 4;
    size_t rem = (ws_size > off) ? (ws_size - off) : 0;
    int nd = (int)(rem / distB);
    if (nd < 1) nd = 1;
    if (nd > N) nd = N;
    float* dist = (float*)alloc(distB * nd);

    hipMemsetAsync(hist, 0, (size_t)N * NBINS * 4, stream);
    hipMemsetAsync(ccnt, 0, (size_t)N * 4, stream);
    hipMemsetAsync(inv, 0xFF, (size_t)N * LPIX * 4, stream);
    hipMemsetAsync(crank, 0xFF, (size_t)N * KSEL * 4, stream);
    hipMemsetAsync(allw, 0, (size_t)N * MCL * 4, stream);
    hipMemsetAsync(merged, 0, (size_t)N * MCL * CCH * 4, stream);

    split_w1<<<256, 256, 0, stream>>>(w1, w1h, w1m, w1l);
    score_mfma<<<dim3(LPIX / 64, N), 256, 0, stream>>>(x, prio, w1h, w1m, w1l, b1, w2, b2, weight, hist);
    thr_kernel<<<N, 256, 0, stream>>>(hist, thrbin);
    cand_kernel<<<dim3((LPIX + 255) / 256, N), 256, 0, stream>>>(weight, thrbin, candw, cidx, ccnt);
    rank_kernel<<<dim3(8192, N), 256, 0, stream>>>(candw, cidx, ccnt, conf, sidx);
    gather_src<<<dim3(KSEL, N), 256, 0, stream>>>(x, sidx, conf, src, srch, srcm, srcl, sq, inv);

    const int TI = (KSEL + 127) / 128;           // 28
    const int NT = TI * (TI + 1) / 2;            // 406 lower-triangle tiles
    for (int g = 0; g < N; g += nd) {
        int nb = (N - g < nd) ? (N - g) : nd;
        dist_mfma<<<dim3(NT, 1, nb), 256, 0, stream>>>(srch, srcm, srcl, sq, dist, g);
        knn_density<<<dim3(KSEL / 4, nb), 256, 0, stream>>>(dist, density, g);
        delta_score<<<dim3(KSEL, nb), 256, 0, stream>>>(dist, density, scoreb, g);
        center_rank<<<dim3(KSEL, nb), 256, 0, stream>>>(scoreb, centers, crank, g);
        assign_kernel<<<dim3(KSEL / 64, nb), 256, 0, stream>>>(dist, centers, crank, conf, clus, allw, g);
        merge_feat<<<dim3(KSEL, nb), 256, 0, stream>>>(src, conf, clus, merged, g);
    }
    merged_div<<<N * MCL, 256, 0, stream>>>(merged, allw);

    float* psm = out + (size_t)N * CCH * LPIX;
    float* rm  = psm + (size_t)B * 2 * LPIX;
    bev_kernel<<<dim3((LPIX / 4 + 255) / 256, N), 256, 0, stream>>>(
        x, inv, clus, merged, reclen, B, clsw, clsb, regw, regb, out, psm, rm);
}

// Round 12
// 1293.025 us; speedup vs baseline: 1.1339x; 1.0030x over previous
//
#include <hip/hip_runtime.h>
#include <hip/hip_bf16.h>

#define CCH   256
#define LPIX  35200
#define KSEL  3520
#define MCL   880
#define NBINS 16384
#define FMAXV 3.402823466e38f

typedef __bf16 bf16x8 __attribute__((ext_vector_type(8)));
typedef float  f32x4  __attribute__((ext_vector_type(4)));
typedef unsigned short ushort_t;

__device__ __forceinline__ void split3(float v, __bf16* h, __bf16* m, __bf16* l) {
    __bf16 a = (__bf16)v;
    float r = v - (float)a;
    __bf16 b = (__bf16)r;
    float r2 = r - (float)b;
    *h = a; *m = b; *l = (__bf16)r2;
}

// 6-term bf16x3 split: per-acc term order hh,hm,mh,hl,mm,lh (error ~2^-24).
// Emitted TERM-MAJOR across all independent accumulators.
__device__ constexpr int SA6[6] = {0, 0, 1, 0, 1, 2};
__device__ constexpr int SB6[6] = {0, 1, 0, 2, 1, 0};

// ---------------- W1 -> bf16x3 splits ----------------
__global__ void split_w1(const float* __restrict__ w1, __bf16* __restrict__ h,
                         __bf16* __restrict__ m, __bf16* __restrict__ l) {
    int i = blockIdx.x * 256 + threadIdx.x;
    split3(w1[i], &h[i], &m[i], &l[i]);
}

// ---------------- score MLP: MFMA bf16x3, BK=64 per barrier (4 barriers total) ----------------
// Xs stride 144B: frag reads and staging writes both map 8 lanes per 4-bank group
// (minimum LDS cycles). Two 32-channel MFMA halves per barrier; W1 frags loaded
// on-demand per half (L2-hot). MFMA order per accumulator unchanged -> bit-identical.
__global__ __launch_bounds__(256) void score_mfma(
    const float* __restrict__ x, const float* __restrict__ prio,
    const __bf16* __restrict__ w1h, const __bf16* __restrict__ w1m, const __bf16* __restrict__ w1l,
    const float* __restrict__ b1, const float* __restrict__ w2, const float* __restrict__ b2,
    float* __restrict__ weight, int* __restrict__ hist) {
    int n = blockIdx.y;
    int l0 = blockIdx.x * 64;
    int tid = threadIdx.x, w = tid >> 6, lane = tid & 63;
    int lrow = lane & 15, kg = lane >> 4;
    __shared__ __align__(16) __bf16 Xs[2][3][64][72];
    __shared__ float spart[64][17];
    const float* xb = x + (size_t)n * CCH * LPIX;
    f32x4 acc[4][4];
#pragma unroll
    for (int i = 0; i < 4; i++)
#pragma unroll
        for (int j = 0; j < 4; j++) acc[i][j] = (f32x4){0.f, 0.f, 0.f, 0.f};

    int sl = tid & 63;   // pixel within tile
    int cg = tid >> 6;   // channel octet selector: octets cg and cg+4 (of 8 per 64-ch tile)

    auto loadx = [&](int k, float* dst) {   // dst[16]
        int c0 = k * 64;
#pragma unroll
        for (int h = 0; h < 2; h++)
#pragma unroll
            for (int j = 0; j < 8; j++)
                dst[h * 8 + j] = xb[(size_t)(c0 + (cg + 4 * h) * 8 + j) * LPIX + l0 + sl];
    };
    auto stage = [&](int buf, const float* v) {
#pragma unroll
        for (int h = 0; h < 2; h++) {
            bf16x8 vh, vm, vl;
#pragma unroll
            for (int j = 0; j < 8; j++) {
                __bf16 hh, mm, ll;
                split3(v[h * 8 + j], &hh, &mm, &ll);
                vh[j] = hh; vm[j] = mm; vl[j] = ll;
            }
            *(bf16x8*)&Xs[buf][0][sl][(cg + 4 * h) * 8] = vh;
            *(bf16x8*)&Xs[buf][1][sl][(cg + 4 * h) * 8] = vm;
            *(bf16x8*)&Xs[buf][2][sl][(cg + 4 * h) * 8] = vl;
        }
    };

    float pf[2][16];
    loadx(0, pf[0]);
    stage(0, pf[0]);
    loadx(1, pf[1]);
    __syncthreads();

#pragma unroll
    for (int k = 0; k < 4; k++) {
        const int buf = k & 1;
        if (k < 3) stage(buf ^ 1, pf[buf ^ 1]);  // split+write tile k+1 -> Xs[buf^1]
        if (k < 2) loadx(k + 2, pf[buf]);        // x tile k+2 (latency hides under MFMAs)
#pragma unroll
        for (int kk = 0; kk < 2; kk++) {
            const int cbase = k * 64 + kk * 32;
            bf16x8 bf[3][4], af[3][4];
#pragma unroll
            for (int fj = 0; fj < 4; fj++) {
                bf[0][fj] = *(const bf16x8*)&Xs[buf][0][fj * 16 + lrow][kk * 32 + kg * 8];
                bf[1][fj] = *(const bf16x8*)&Xs[buf][1][fj * 16 + lrow][kk * 32 + kg * 8];
                bf[2][fj] = *(const bf16x8*)&Xs[buf][2][fj * 16 + lrow][kk * 32 + kg * 8];
            }
#pragma unroll
            for (int fi = 0; fi < 4; fi++) {
                size_t ao = (size_t)(w * 64 + fi * 16 + lrow) * 256 + cbase + kg * 8;
                af[0][fi] = *(const bf16x8*)&w1h[ao];
                af[1][fi] = *(const bf16x8*)&w1m[ao];
                af[2][fi] = *(const bf16x8*)&w1l[ao];
            }
            // term-major: 16 independent accs between writes to any single acc
#pragma unroll
            for (int t = 0; t < 6; t++) {
#pragma unroll
                for (int fi = 0; fi < 4; fi++) {
#pragma unroll
                    for (int fj = 0; fj < 4; fj++) {
                        acc[fi][fj] = __builtin_amdgcn_mfma_f32_16x16x32_bf16(
                            af[SA6[t]][fi], bf[SB6[t]][fj], acc[fi][fj], 0, 0, 0);
                    }
                }
            }
        }
        __syncthreads();
    }

    float ps[4] = {0.f, 0.f, 0.f, 0.f};
#pragma unroll
    for (int fi = 0; fi < 4; fi++) {
        int ob = w * 64 + fi * 16 + kg * 4;
        float4 b1v = *(const float4*)&b1[ob];
        float4 w2v = *(const float4*)&w2[ob];
        float b1a[4] = {b1v.x, b1v.y, b1v.z, b1v.w};
        float w2a[4] = {w2v.x, w2v.y, w2v.z, w2v.w};
#pragma unroll
        for (int r = 0; r < 4; r++)
#pragma unroll
            for (int fj = 0; fj < 4; fj++)
                ps[fj] += w2a[r] * fmaxf(acc[fi][fj][r] + b1a[r], 0.f);
    }
#pragma unroll
    for (int fj = 0; fj < 4; fj++) spart[fj * 16 + lrow][w * 4 + kg] = ps[fj];
    __syncthreads();
    if (tid < 64) {
        float s = 0.f;
#pragma unroll
        for (int r = 0; r < 16; r++) s += spart[tid][r];
        s += b2[0];
        float sg = 1.f / (1.f + expf(-s));
        float wv = sg * prio[(size_t)n * LPIX + l0 + tid];
        weight[(size_t)n * LPIX + l0 + tid] = wv;
        int b = (int)(wv * (float)NBINS);
        b = min(max(b, 0), NBINS - 1);
        atomicAdd(&hist[(size_t)n * NBINS + b], 1);
    }
}

__global__ __launch_bounds__(256) void thr_kernel(const int* __restrict__ hist, int* __restrict__ thrbin) {
    int n = blockIdx.x, t = threadIdx.x;
    const int CH = NBINS / 256;
    __shared__ int csum[256];
    __shared__ int bfound;
    int base = NBINS - (t + 1) * CH;
    int s = 0;
    for (int i = 0; i < CH; i++) s += hist[(size_t)n * NBINS + base + i];
    csum[t] = s;
    __syncthreads();
    if (t == 0) {
        int cum = 0, sel = 255;
        for (int u = 0; u < 256; u++) {
            cum += csum[u];
            csum[u] = cum;
            if (cum >= KSEL) { sel = u; break; }
        }
        bfound = sel;
    }
    __syncthreads();
    if (t == 0) {
        int u = bfound;
        int cumBefore = (u == 0) ? 0 : csum[u - 1];
        int base2 = NBINS - (u + 1) * CH;
        int cum = cumBefore, bsel = base2;
        for (int b = base2 + CH - 1; b >= base2; b--) {
            cum += hist[(size_t)n * NBINS + b];
            if (cum >= KSEL) { bsel = b; break; }
        }
        thrbin[n] = bsel;
    }
}

__global__ void cand_kernel(const float* __restrict__ weight, const int* __restrict__ thrbin,
                            float* __restrict__ candw, int* __restrict__ cidx, int* __restrict__ ccnt) {
    int n = blockIdx.y;
    int i = blockIdx.x * 256 + threadIdx.x;
    if (i >= LPIX) return;
    float w = weight[(size_t)n * LPIX + i];
    int b = (int)(w * (float)NBINS);
    b = min(max(b, 0), NBINS - 1);
    if (b >= thrbin[n]) {
        int p = atomicAdd(&ccnt[n], 1);
        candw[(size_t)n * LPIX + p] = w;
        cidx[(size_t)n * LPIX + p] = i;
    }
}

__global__ __launch_bounds__(256) void rank_kernel(const float* __restrict__ candw, const int* __restrict__ cidx,
                                                   const int* __restrict__ ccnt,
                                                   float* __restrict__ conf, int* __restrict__ sidx) {
    int n = blockIdx.y, i = blockIdx.x;
    int cnt = ccnt[n];
    if (i >= cnt) return;
    float wi = candw[(size_t)n * LPIX + i];
    int ii = cidx[(size_t)n * LPIX + i];
    int r = 0;
    for (int j = threadIdx.x; j < cnt; j += 256) {
        float wj = candw[(size_t)n * LPIX + j];
        int ij = cidx[(size_t)n * LPIX + j];
        if (wj > wi || (wj == wi && ij < ii)) r++;
    }
    __shared__ int red[256];
    red[threadIdx.x] = r;
    __syncthreads();
    for (int s = 128; s > 0; s >>= 1) {
        if (threadIdx.x < s) red[threadIdx.x] += red[threadIdx.x + s];
        __syncthreads();
    }
    if (threadIdx.x == 0) {
        int rank = red[0];
        if (rank < KSEL) {
            sidx[(size_t)n * KSEL + rank] = ii;
            conf[(size_t)n * KSEL + rank] = wi;
        }
    }
}

// ---------------- gather selected tokens + bf16x3 splits + sq + inverse map ----------------
__global__ __launch_bounds__(256) void gather_src(const float* __restrict__ x, const int* __restrict__ sidx,
                                                  const float* __restrict__ conf,
                                                  float* __restrict__ src,
                                                  __bf16* __restrict__ sh, __bf16* __restrict__ sm,
                                                  __bf16* __restrict__ sl,
                                                  float* __restrict__ sq, int* __restrict__ inv) {
    int n = blockIdx.y, k = blockIdx.x, c = threadIdx.x;
    int idx = sidx[(size_t)n * KSEL + k];
    float cf = conf[(size_t)n * KSEL + k];
    float v = x[((size_t)n * CCH + c) * LPIX + idx] * cf;
    size_t o = ((size_t)n * KSEL + k) * CCH + c;
    src[o] = v;
    __bf16 h, m, l;
    split3(v, &h, &m, &l);
    sh[o] = h; sm[o] = m; sl[o] = l;
    __shared__ float red[256];
    red[c] = v * v;
    __syncthreads();
    for (int s = 128; s > 0; s >>= 1) {
        if (c < s) red[c] += red[c + s];
        __syncthreads();
    }
    if (c == 0) {
        sq[(size_t)n * KSEL + k] = red[0];
        inv[(size_t)n * LPIX + idx] = k;
    }
}

// ---------------- dist GEMM: MFMA bf16x3, triangular + mirror, XCD-swizzled tiles ----------------
__global__ __launch_bounds__(256) void dist_mfma(
    const __bf16* __restrict__ sh, const __bf16* __restrict__ sm, const __bf16* __restrict__ sl,
    const float* __restrict__ sq, float* __restrict__ dist, int n0) {
    int n = n0 + blockIdx.z;
    const size_t nbase = (size_t)n * KSEL * CCH;
    const float* sqn = sq + (size_t)n * KSEL;
    float* D = dist + (size_t)blockIdx.z * KSEL * KSEL;
    // bijective XCD swizzle over NT=406 tiles (q=50, r=6): XCD k gets ~51
    // consecutive triangular indices -> A-panel reuse lands in the same L2.
    int orig = blockIdx.x;
    int xcd = orig & 7, loc = orig >> 3;
    int b = (xcd < 6 ? xcd * 51 : 306 + (xcd - 6) * 50) + loc;
    int iT = (int)((sqrtf(8.f * (float)b + 1.f) - 1.f) * 0.5f);
    while ((iT + 1) * (iT + 2) / 2 <= b) iT++;
    while (iT * (iT + 1) / 2 > b) iT--;
    int jT = b - iT * (iT + 1) / 2;
    int bi = iT * 128, bj = jT * 128;
    __shared__ __align__(16) __bf16 As[3][128][40], Bs[3][128][40];
    int tid = threadIdx.x, w = tid >> 6, lane = tid & 63;
    int lrow = lane & 15, kg = lane >> 4;
    int wr = w >> 1, wc = w & 1;
    f32x4 acc[4][4];
#pragma unroll
    for (int i = 0; i < 4; i++)
#pragma unroll
        for (int j = 0; j < 4; j++) acc[i][j] = (f32x4){0.f, 0.f, 0.f, 0.f};

    int sr = tid & 127, g2 = tid >> 7;
    size_t ra = nbase + (size_t)min(bi + sr, KSEL - 1) * CCH;
    size_t rb = nbase + (size_t)min(bj + sr, KSEL - 1) * CCH;

    bf16x8 rA[3][2], rB[3][2];
#pragma unroll
    for (int s2 = 0; s2 < 2; s2++) {
        int cg = s2 * 2 + g2;
        rA[0][s2] = *(const bf16x8*)&sh[ra + cg * 8];
        rA[1][s2] = *(const bf16x8*)&sm[ra + cg * 8];
        rA[2][s2] = *(const bf16x8*)&sl[ra + cg * 8];
        rB[0][s2] = *(const bf16x8*)&sh[rb + cg * 8];
        rB[1][s2] = *(const bf16x8*)&sm[rb + cg * 8];
        rB[2][s2] = *(const bf16x8*)&sl[rb + cg * 8];
    }
    for (int c0 = 0; c0 < 256; c0 += 32) {
        __syncthreads();
#pragma unroll
        for (int s2 = 0; s2 < 2; s2++) {
            int cg = s2 * 2 + g2;
            *(bf16x8*)&As[0][sr][cg * 8] = rA[0][s2];
            *(bf16x8*)&As[1][sr][cg * 8] = rA[1][s2];
            *(bf16x8*)&As[2][sr][cg * 8] = rA[2][s2];
            *(bf16x8*)&Bs[0][sr][cg * 8] = rB[0][s2];
            *(bf16x8*)&Bs[1][sr][cg * 8] = rB[1][s2];
            *(bf16x8*)&Bs[2][sr][cg * 8] = rB[2][s2];
        }
        __syncthreads();
        if (c0 < 224) {
            int c1 = c0 + 32;
#pragma unroll
            for (int s2 = 0; s2 < 2; s2++) {
                int cg = s2 * 2 + g2;
                rA[0][s2] = *(const bf16x8*)&sh[ra + c1 + cg * 8];
                rA[1][s2] = *(const bf16x8*)&sm[ra + c1 + cg * 8];
                rA[2][s2] = *(const bf16x8*)&sl[ra + c1 + cg * 8];
                rB[0][s2] = *(const bf16x8*)&sh[rb + c1 + cg * 8];
                rB[1][s2] = *(const bf16x8*)&sm[rb + c1 + cg * 8];
                rB[2][s2] = *(const bf16x8*)&sl[rb + c1 + cg * 8];
            }
        }
        bf16x8 af[3][4], bf[3][4];
#pragma unroll
        for (int fj = 0; fj < 4; fj++) {
            int brow = wc * 64 + fj * 16 + lrow;
            bf[0][fj] = *(const bf16x8*)&Bs[0][brow][kg * 8];
            bf[1][fj] = *(const bf16x8*)&Bs[1][brow][kg * 8];
            bf[2][fj] = *(const bf16x8*)&Bs[2][brow][kg * 8];
        }
#pragma unroll
        for (int fi = 0; fi < 4; fi++) {
            int arow = wr * 64 + fi * 16 + lrow;
            af[0][fi] = *(const bf16x8*)&As[0][arow][kg * 8];
            af[1][fi] = *(const bf16x8*)&As[1][arow][kg * 8];
            af[2][fi] = *(const bf16x8*)&As[2][arow][kg * 8];
        }
#pragma unroll
        for (int t = 0; t < 6; t++) {
#pragma unroll
            for (int fi = 0; fi < 4; fi++) {
#pragma unroll
                for (int fj = 0; fj < 4; fj++) {
                    acc[fi][fj] = __builtin_amdgcn_mfma_f32_16x16x32_bf16(
                        af[SA6[t]][fi], bf[SB6[t]][fj], acc[fi][fj], 0, 0, 0);
                }
            }
        }
    }
#pragma unroll
    for (int fi = 0; fi < 4; fi++) {
        int gi0 = bi + wr * 64 + fi * 16;
        if (gi0 >= KSEL) continue;
        float4 siv = *(const float4*)&sqn[gi0 + kg * 4];
        float sia[4] = {siv.x, siv.y, siv.z, siv.w};
#pragma unroll
        for (int fj = 0; fj < 4; fj++) {
            int gj0 = bj + wc * 64 + fj * 16;
            if (gj0 >= KSEL) continue;
            int gj = gj0 + lrow;
            float sj = sqn[gj];
            float dv[4];
#pragma unroll
            for (int r = 0; r < 4; r++) {
                int gi = gi0 + kg * 4 + r;
                dv[r] = fmaxf(sia[r] + sj - 2.f * acc[fi][fj][r], 0.f);
                D[(size_t)gi * KSEL + gj] = dv[r];
            }
            if (iT != jT) {
                *(float4*)&D[(size_t)gj * KSEL + gi0 + kg * 4] = *(float4*)dv;
            }
        }
    }
}

// ---------------- density: 4 rows/block, 64 lanes/row, float4 + in-place LDS merge ----------------
__global__ __launch_bounds__(256) void knn_density(const float* __restrict__ dist, float* __restrict__ density, int n0) {
    int n = n0 + blockIdx.y;
    int row = threadIdx.x >> 6;
    int lane = threadIdx.x & 63;
    int i = blockIdx.x * 4 + row;
    const float4* row4 = (const float4*)(dist + (size_t)blockIdx.y * KSEL * KSEL + (size_t)i * KSEL);
    float tt[10];
#pragma unroll
    for (int r = 0; r < 10; r++) tt[r] = FMAXV;
    for (int j4 = lane; j4 < KSEL / 4; j4 += 64) {
        float4 v4 = row4[j4];
        float vv[4] = {v4.x, v4.y, v4.z, v4.w};
#pragma unroll
        for (int q = 0; q < 4; q++) {
            float v = vv[q];
            if (v < tt[9]) {
                tt[9] = v;
#pragma unroll
                for (int r = 9; r > 0; r--) {
                    if (tt[r] < tt[r - 1]) { float tmp = tt[r - 1]; tt[r - 1] = tt[r]; tt[r] = tmp; }
                }
            }
        }
    }
    __shared__ float ls[4][64][10];
#pragma unroll
    for (int r = 0; r < 10; r++) ls[row][lane][r] = tt[r];
    __syncthreads();
    for (int s = 32; s >= 1; s >>= 1) {
        if (lane < s) {
            float out[10];
            int ia = 0, ib = 0;
#pragma unroll
            for (int r = 0; r < 10; r++) {
                float va = ls[row][lane][ia], vb = ls[row][lane + s][ib];
                if (va <= vb) { out[r] = va; ia++; } else { out[r] = vb; ib++; }
            }
#pragma unroll
            for (int r = 0; r < 10; r++) ls[row][lane][r] = out[r];
        }
        __syncthreads();
    }
    if (lane == 0) {
        float sum = 0.f;
#pragma unroll
        for (int r = 0; r < 10; r++) sum += ls[row][0][r];
        density[(size_t)n * KSEL + i] = expf(-sum * 0.1f) + (float)i * 1e-6f;
    }
}

// ---------------- delta & score (marker token -> +inf score) ----------------
__global__ __launch_bounds__(256) void delta_score(const float* __restrict__ dist, const float* __restrict__ density,
                                                   float* __restrict__ scoreb, int n0) {
    int n = n0 + blockIdx.y;
    int i = blockIdx.x;
    const float4* row = (const float4*)(dist + (size_t)blockIdx.y * KSEL * KSEL + (size_t)i * KSEL);
    const float* dn = density + (size_t)n * KSEL;
    const float4* dn4 = (const float4*)dn;
    float di = dn[i];
    float mn = FMAXV;
    for (int j4 = threadIdx.x; j4 < KSEL / 4; j4 += 256) {
        float4 d = dn4[j4];
        float4 v = row[j4];
        if (d.x > di) mn = fminf(mn, v.x);
        if (d.y > di) mn = fminf(mn, v.y);
        if (d.z > di) mn = fminf(mn, v.z);
        if (d.w > di) mn = fminf(mn, v.w);
    }
    __shared__ float red[256];
    red[threadIdx.x] = mn;
    __syncthreads();
    for (int s = 128; s > 0; s >>= 1) {
        if (threadIdx.x < s) red[threadIdx.x] = fminf(red[threadIdx.x], red[threadIdx.x + s]);
        __syncthreads();
    }
    if (threadIdx.x == 0) {
        float d = red[0];
        scoreb[(size_t)n * KSEL + i] = (d == FMAXV) ? FMAXV : d * di;
    }
}

__global__ __launch_bounds__(256) void center_rank(const float* __restrict__ scoreb, int* __restrict__ centers,
                                                   int* __restrict__ crank, int n0) {
    int n = n0 + blockIdx.y;
    int i = blockIdx.x;
    const float* sc = scoreb + (size_t)n * KSEL;
    float si = sc[i];
    int r = 0;
    for (int j = threadIdx.x; j < KSEL; j += 256) {
        float sj = sc[j];
        if (sj > si || (sj == si && j < i)) r++;
    }
    __shared__ int red[256];
    red[threadIdx.x] = r;
    __syncthreads();
    for (int s = 128; s > 0; s >>= 1) {
        if (threadIdx.x < s) red[threadIdx.x] += red[threadIdx.x + s];
        __syncthreads();
    }
    if (threadIdx.x == 0) {
        int rank = red[0];
        if (rank < MCL) {
            centers[(size_t)n * MCL + rank] = i;
            crank[(size_t)n * KSEL + i] = rank;
        }
    }
}

// ---------------- assign + fused merge_w ----------------
__global__ __launch_bounds__(256) void assign_kernel(const float* __restrict__ dist, const int* __restrict__ centers,
                                                     const int* __restrict__ crank, const float* __restrict__ conf,
                                                     int* __restrict__ clus, float* __restrict__ allw, int n0) {
    int n = n0 + blockIdx.y;
    const float* D = dist + (size_t)blockIdx.y * KSEL * KSEL;
    int kl = threadIdx.x & 63, mc = threadIdx.x >> 6;
    int k = blockIdx.x * 64 + kl;
    const int* ctr = centers + (size_t)n * MCL;
    float mn = FMAXV;
    int am = MCL;
    for (int m = mc * 220; m < (mc + 1) * 220; m++) {
        float v = D[(size_t)ctr[m] * KSEL + k];
        if (v < mn) { mn = v; am = m; }
    }
    __shared__ float mv[4][64];
    __shared__ int mi[4][64];
    mv[mc][kl] = mn;
    mi[mc][kl] = am;
    __syncthreads();
    if (mc == 0) {
        float best = mv[0][kl];
        int bm = mi[0][kl];
#pragma unroll
        for (int c = 1; c < 4; c++) {
            float v = mv[c][kl];
            int im = mi[c][kl];
            if (v < best || (v == best && im < bm)) { best = v; bm = im; }
        }
        int cr = crank[(size_t)n * KSEL + k];
        int cl = (cr >= 0) ? cr : bm;
        clus[(size_t)n * KSEL + k] = cl;
        atomicAdd(&allw[(size_t)n * MCL + cl], conf[(size_t)n * KSEL + k]);
    }
}

__global__ void merge_feat(const float* __restrict__ src, const float* __restrict__ conf,
                           const int* __restrict__ clus, float* __restrict__ merged, int n0) {
    int n = n0 + blockIdx.y;
    int k = blockIdx.x, c = threadIdx.x;
    float v = src[((size_t)n * KSEL + k) * CCH + c] * conf[(size_t)n * KSEL + k];
    atomicAdd(&merged[((size_t)n * MCL + clus[(size_t)n * KSEL + k]) * CCH + c], v);
}

__global__ void merged_div(float* __restrict__ merged, const float* __restrict__ allw) {
    int nm = blockIdx.x, c = threadIdx.x;
    merged[(size_t)nm * CCH + c] /= (allw[nm] + 1e-6f);
}

// ---------------- bev + fused ego heads: one pass over x ----------------
__global__ __launch_bounds__(256) void bev_kernel(const float* __restrict__ x, const int* __restrict__ inv,
                                                  const int* __restrict__ clus, const float* __restrict__ merged,
                                                  const int* __restrict__ reclen, int B,
                                                  const float* __restrict__ clsw, const float* __restrict__ clsb,
                                                  const float* __restrict__ regw, const float* __restrict__ regb,
                                                  float* __restrict__ out, float* __restrict__ psm,
                                                  float* __restrict__ rm) {
    int n = blockIdx.y;
    int l0 = (blockIdx.x * 256 + threadIdx.x) * 4;
    bool ego = false;
    int bego = 0;
    {
        int off = 0;
        for (int b = 0; b < B; b++) {
            if (n == off) { ego = true; bego = b; break; }
            off += reclen[b];
        }
    }
    __shared__ float ws[16][256];
    __shared__ float bs[16];
    if (ego) {
        for (int i = threadIdx.x; i < 16 * 256; i += 256) {
            int o = i >> 8, c = i & 255;
            ws[o][c] = (o < 2) ? clsw[o * 256 + c] : regw[(o - 2) * 256 + c];
        }
        if (threadIdx.x < 16) bs[threadIdx.x] = (threadIdx.x < 2) ? clsb[threadIdx.x] : regb[threadIdx.x - 2];
        __syncthreads();
    }
    if (l0 >= LPIX) return;
    size_t base = (size_t)n * CCH * LPIX + l0;
    if (ego) {
        float acc[16][4] = {};
        for (int c = 0; c < CCH; c++) {
            float4 v = *(const float4*)&x[base + (size_t)c * LPIX];
            *(float4*)&out[base + (size_t)c * LPIX] = v;
#pragma unroll
            for (int o = 0; o < 16; o++) {
                float wv = ws[o][c];
                acc[o][0] += wv * v.x; acc[o][1] += wv * v.y; acc[o][2] += wv * v.z; acc[o][3] += wv * v.w;
            }
        }
#pragma unroll
        for (int o = 0; o < 2; o++) {
            float4 r;
            r.x = acc[o][0] + bs[o]; r.y = acc[o][1] + bs[o]; r.z = acc[o][2] + bs[o]; r.w = acc[o][3] + bs[o];
            *(float4*)&psm[((size_t)bego * 2 + o) * LPIX + l0] = r;
        }
#pragma unroll
        for (int o = 0; o < 14; o++) {
            float4 r;
            float bb = bs[o + 2];
            r.x = acc[o + 2][0] + bb; r.y = acc[o + 2][1] + bb; r.z = acc[o + 2][2] + bb; r.w = acc[o + 2][3] + bb;
            *(float4*)&rm[((size_t)bego * 14 + o) * LPIX + l0] = r;
        }
    } else {
        const float* mr0; const float* mr1; const float* mr2; const float* mr3;
        {
            int t0 = inv[(size_t)n * LPIX + l0 + 0];
            int t1 = inv[(size_t)n * LPIX + l0 + 1];
            int t2 = inv[(size_t)n * LPIX + l0 + 2];
            int t3 = inv[(size_t)n * LPIX + l0 + 3];
            mr0 = (t0 >= 0) ? merged + ((size_t)n * MCL + clus[(size_t)n * KSEL + t0]) * CCH : nullptr;
            mr1 = (t1 >= 0) ? merged + ((size_t)n * MCL + clus[(size_t)n * KSEL + t1]) * CCH : nullptr;
            mr2 = (t2 >= 0) ? merged + ((size_t)n * MCL + clus[(size_t)n * KSEL + t2]) * CCH : nullptr;
            mr3 = (t3 >= 0) ? merged + ((size_t)n * MCL + clus[(size_t)n * KSEL + t3]) * CCH : nullptr;
        }
        for (int c = 0; c < CCH; c++) {
            float4 v;
            v.x = mr0 ? mr0[c] : 0.f;
            v.y = mr1 ? mr1[c] : 0.f;
            v.z = mr2 ? mr2[c] : 0.f;
            v.w = mr3 ? mr3[c] : 0.f;
            *(float4*)&out[base + (size_t)c * LPIX] = v;
        }
    }
}

extern "C" void kernel_launch(void* const* d_in, const int* in_sizes, int n_in,
                              void* d_out, int out_size, void* d_ws, size_t ws_size,
                              hipStream_t stream) {
    const float* x    = (const float*)d_in[0];
    const float* prio = (const float*)d_in[1];
    const float* w1   = (const float*)d_in[2];
    const float* b1   = (const float*)d_in[3];
    const float* w2   = (const float*)d_in[4];
    const float* b2   = (const float*)d_in[5];
    const float* clsw = (const float*)d_in[6];
    const float* clsb = (const float*)d_in[7];
    const float* regw = (const float*)d_in[8];
    const float* regb = (const float*)d_in[9];
    const int* reclen = (const int*)d_in[10];
    int N = in_sizes[0] / (CCH * LPIX);
    int B = in_sizes[10];
    float* out = (float*)d_out;

    char* p = (char*)d_ws;
    size_t off = 0;
    auto alloc = [&](size_t bytes) -> void* {
        void* r = p + off;
        off += (bytes + 255) & ~(size_t)255;
        return r;
    };
    __bf16* w1h    = (__bf16*)alloc(256 * 256 * 2);
    __bf16* w1m    = (__bf16*)alloc(256 * 256 * 2);
    __bf16* w1l    = (__bf16*)alloc(256 * 256 * 2);
    float* weight  = (float*)alloc((size_t)N * LPIX * 4);
    int*   hist    = (int*)alloc((size_t)N * NBINS * 4);
    int*   thrbin  = (int*)alloc((size_t)N * 4);
    int*   ccnt    = (int*)alloc((size_t)N * 4);
    float* candw   = (float*)alloc((size_t)N * LPIX * 4);
    int*   cidx    = (int*)alloc((size_t)N * LPIX * 4);
    int*   sidx    = (int*)alloc((size_t)N * KSEL * 4);
    float* conf    = (float*)alloc((size_t)N * KSEL * 4);
    float* src     = (float*)alloc((size_t)N * KSEL * CCH * 4);
    __bf16* srch   = (__bf16*)alloc((size_t)N * KSEL * CCH * 2);
    __bf16* srcm   = (__bf16*)alloc((size_t)N * KSEL * CCH * 2);
    __bf16* srcl   = (__bf16*)alloc((size_t)N * KSEL * CCH * 2);
    float* sq      = (float*)alloc((size_t)N * KSEL * 4);
    int*   inv     = (int*)alloc((size_t)N * LPIX * 4);
    float* density = (float*)alloc((size_t)N * KSEL * 4);
    float* scoreb  = (float*)alloc((size_t)N * KSEL * 4);
    int*   centers = (int*)alloc((size_t)N * MCL * 4);
    int*   crank   = (int*)alloc((size_t)N * KSEL * 4);
    int*   clus    = (int*)alloc((size_t)N * KSEL * 4);
    float* allw    = (float*)alloc((size_t)N * MCL * 4);
    float* merged  = (float*)alloc((size_t)N * MCL * CCH * 4);
    const size_t distB = (size_t)KSEL * KSEL * 4;
    size_t rem = (ws_size > off) ? (ws_size - off) : 0;
    int nd = (int)(rem / distB);
    if (nd < 1) nd = 1;
    if (nd > N) nd = N;
    float* dist = (float*)alloc(distB * nd);

    hipMemsetAsync(hist, 0, (size_t)N * NBINS * 4, stream);
    hipMemsetAsync(ccnt, 0, (size_t)N * 4, stream);
    hipMemsetAsync(inv, 0xFF, (size_t)N * LPIX * 4, stream);
    hipMemsetAsync(crank, 0xFF, (size_t)N * KSEL * 4, stream);
    hipMemsetAsync(allw, 0, (size_t)N * MCL * 4, stream);
    hipMemsetAsync(merged, 0, (size_t)N * MCL * CCH * 4, stream);

    split_w1<<<256, 256, 0, stream>>>(w1, w1h, w1m, w1l);
    score_mfma<<<dim3(LPIX / 64, N), 256, 0, stream>>>(x, prio, w1h, w1m, w1l, b1, w2, b2, weight, hist);
    thr_kernel<<<N, 256, 0, stream>>>(hist, thrbin);
    cand_kernel<<<dim3((LPIX + 255) / 256, N), 256, 0, stream>>>(weight, thrbin, candw, cidx, ccnt);
    rank_kernel<<<dim3(8192, N), 256, 0, stream>>>(candw, cidx, ccnt, conf, sidx);
    gather_src<<<dim3(KSEL, N), 256, 0, stream>>>(x, sidx, conf, src, srch, srcm, srcl, sq, inv);

    const int TI = (KSEL + 127) / 128;           // 28
    const int NT = TI * (TI + 1) / 2;            // 406 lower-triangle tiles
    for (int g = 0; g < N; g += nd) {
        int nb = (N - g < nd) ? (N - g) : nd;
        dist_mfma<<<dim3(NT, 1, nb), 256, 0, stream>>>(srch, srcm, srcl, sq, dist, g);
        knn_density<<<dim3(KSEL / 4, nb), 256, 0, stream>>>(dist, density, g);
        delta_score<<<dim3(KSEL, nb), 256, 0, stream>>>(dist, density, scoreb, g);
        center_rank<<<dim3(KSEL, nb), 256, 0, stream>>>(scoreb, centers, crank, g);
        assign_kernel<<<dim3(KSEL / 64, nb), 256, 0, stream>>>(dist, centers, crank, conf, clus, allw, g);
        merge_feat<<<dim3(KSEL, nb), 256, 0, stream>>>(src, conf, clus, merged, g);
    }
    merged_div<<<N * MCL, 256, 0, stream>>>(merged, allw);

    float* psm = out + (size_t)N * CCH * LPIX;
    float* rm  = psm + (size_t)B * 2 * LPIX;
    bev_kernel<<<dim3((LPIX / 4 + 255) / 256, N), 256, 0, stream>>>(
        x, inv, clus, merged, reclen, B, clsw, clsb, regw, regb, out, psm, rm);
}

// Round 13
// 1281.524 us; speedup vs baseline: 1.1441x; 1.0090x over previous
//
#include <hip/hip_runtime.h>
#include <hip/hip_bf16.h>

#define CCH   256
#define LPIX  35200
#define KSEL  3520
#define MCL   880
#define NBINS 16384
#define FMAXV 3.402823466e38f

typedef __bf16 bf16x8 __attribute__((ext_vector_type(8)));
typedef float  f32x4  __attribute__((ext_vector_type(4)));
typedef unsigned short ushort_t;

__device__ __forceinline__ void split3(float v, __bf16* h, __bf16* m, __bf16* l) {
    __bf16 a = (__bf16)v;
    float r = v - (float)a;
    __bf16 b = (__bf16)r;
    float r2 = r - (float)b;
    *h = a; *m = b; *l = (__bf16)r2;
}

// 6-term bf16x3 split: per-acc term order hh,hm,mh,hl,mm,lh (error ~2^-24).
// Emitted TERM-MAJOR across all independent accumulators.
__device__ constexpr int SA6[6] = {0, 0, 1, 0, 1, 2};
__device__ constexpr int SB6[6] = {0, 1, 0, 2, 1, 0};

// ---------------- W1 -> bf16x3 splits ----------------
__global__ void split_w1(const float* __restrict__ w1, __bf16* __restrict__ h,
                         __bf16* __restrict__ m, __bf16* __restrict__ l) {
    int i = blockIdx.x * 256 + threadIdx.x;
    split3(w1[i], &h[i], &m[i], &l[i]);
}

// ---------------- score MLP: MFMA bf16x3, BK=32 pipelined (best measured: 279us) ----------------
__global__ __launch_bounds__(256) void score_mfma(
    const float* __restrict__ x, const float* __restrict__ prio,
    const __bf16* __restrict__ w1h, const __bf16* __restrict__ w1m, const __bf16* __restrict__ w1l,
    const float* __restrict__ b1, const float* __restrict__ w2, const float* __restrict__ b2,
    float* __restrict__ weight, int* __restrict__ hist) {
    int n = blockIdx.y;
    int l0 = blockIdx.x * 64;
    int tid = threadIdx.x, w = tid >> 6, lane = tid & 63;
    int lrow = lane & 15, kg = lane >> 4;
    __shared__ __align__(16) __bf16 Xs[2][3][64][40];
    __shared__ float spart[64][17];
    const float* xb = x + (size_t)n * CCH * LPIX;
    f32x4 acc[4][4];
#pragma unroll
    for (int i = 0; i < 4; i++)
#pragma unroll
        for (int j = 0; j < 4; j++) acc[i][j] = (f32x4){0.f, 0.f, 0.f, 0.f};

    int sl = tid & 63;   // pixel within tile
    int cg = tid >> 6;   // channel octet (8 channels each, 32 per k-step)

    auto loadx = [&](int k, float* dst) {
        int c0 = k * 32 + cg * 8;
#pragma unroll
        for (int j = 0; j < 8; j++)
            dst[j] = xb[(size_t)(c0 + j) * LPIX + l0 + sl];
    };
    auto loadw = [&](int k, bf16x8* dst) {
#pragma unroll
        for (int fi = 0; fi < 4; fi++) {
            size_t ao = (size_t)(w * 64 + fi * 16 + lrow) * 256 + k * 32 + kg * 8;
            dst[fi * 3 + 0] = *(const bf16x8*)&w1h[ao];
            dst[fi * 3 + 1] = *(const bf16x8*)&w1m[ao];
            dst[fi * 3 + 2] = *(const bf16x8*)&w1l[ao];
        }
    };
    auto stage = [&](int buf, const float* v) {
        bf16x8 vh, vm, vl;
#pragma unroll
        for (int j = 0; j < 8; j++) {
            __bf16 h, m, l;
            split3(v[j], &h, &m, &l);
            vh[j] = h; vm[j] = m; vl[j] = l;
        }
        *(bf16x8*)&Xs[buf][0][sl][cg * 8] = vh;
        *(bf16x8*)&Xs[buf][1][sl][cg * 8] = vm;
        *(bf16x8*)&Xs[buf][2][sl][cg * 8] = vl;
    };

    float pf[2][8];
    bf16x8 wfr[2][12];
    loadx(0, pf[0]);
    loadw(0, wfr[0]);
    stage(0, pf[0]);
    loadx(1, pf[1]);
    __syncthreads();

#pragma unroll
    for (int k = 0; k < 8; k++) {
        const int buf = k & 1;
        bf16x8 bf[3][4];
#pragma unroll
        for (int fj = 0; fj < 4; fj++) {
            bf[0][fj] = *(const bf16x8*)&Xs[buf][0][fj * 16 + lrow][kg * 8];
            bf[1][fj] = *(const bf16x8*)&Xs[buf][1][fj * 16 + lrow][kg * 8];
            bf[2][fj] = *(const bf16x8*)&Xs[buf][2][fj * 16 + lrow][kg * 8];
        }
        if (k < 7) loadw(k + 1, wfr[buf ^ 1]);   // W1 for next step (hides under MFMA)
        if (k < 6) loadx(k + 2, pf[buf]);        // x tile k+2
        if (k < 7) stage(buf ^ 1, pf[buf ^ 1]);  // split+write tile k+1 (conflict-free b128)
        // term-major: 16 independent accs between writes to any single acc
#pragma unroll
        for (int t = 0; t < 6; t++) {
#pragma unroll
            for (int fi = 0; fi < 4; fi++) {
#pragma unroll
                for (int fj = 0; fj < 4; fj++) {
                    acc[fi][fj] = __builtin_amdgcn_mfma_f32_16x16x32_bf16(
                        wfr[buf][fi * 3 + SA6[t]], bf[SB6[t]][fj], acc[fi][fj], 0, 0, 0);
                }
            }
        }
        __syncthreads();
    }

    float ps[4] = {0.f, 0.f, 0.f, 0.f};
#pragma unroll
    for (int fi = 0; fi < 4; fi++) {
        int ob = w * 64 + fi * 16 + kg * 4;
        float4 b1v = *(const float4*)&b1[ob];
        float4 w2v = *(const float4*)&w2[ob];
        float b1a[4] = {b1v.x, b1v.y, b1v.z, b1v.w};
        float w2a[4] = {w2v.x, w2v.y, w2v.z, w2v.w};
#pragma unroll
        for (int r = 0; r < 4; r++)
#pragma unroll
            for (int fj = 0; fj < 4; fj++)
                ps[fj] += w2a[r] * fmaxf(acc[fi][fj][r] + b1a[r], 0.f);
    }
#pragma unroll
    for (int fj = 0; fj < 4; fj++) spart[fj * 16 + lrow][w * 4 + kg] = ps[fj];
    __syncthreads();
    if (tid < 64) {
        float s = 0.f;
#pragma unroll
        for (int r = 0; r < 16; r++) s += spart[tid][r];
        s += b2[0];
        float sg = 1.f / (1.f + expf(-s));
        float wv = sg * prio[(size_t)n * LPIX + l0 + tid];
        weight[(size_t)n * LPIX + l0 + tid] = wv;
        int b = (int)(wv * (float)NBINS);
        b = min(max(b, 0), NBINS - 1);
        atomicAdd(&hist[(size_t)n * NBINS + b], 1);
    }
}

__global__ __launch_bounds__(256) void thr_kernel(const int* __restrict__ hist, int* __restrict__ thrbin) {
    int n = blockIdx.x, t = threadIdx.x;
    const int CH = NBINS / 256;
    __shared__ int csum[256];
    __shared__ int bfound;
    int base = NBINS - (t + 1) * CH;
    int s = 0;
    for (int i = 0; i < CH; i++) s += hist[(size_t)n * NBINS + base + i];
    csum[t] = s;
    __syncthreads();
    if (t == 0) {
        int cum = 0, sel = 255;
        for (int u = 0; u < 256; u++) {
            cum += csum[u];
            csum[u] = cum;
            if (cum >= KSEL) { sel = u; break; }
        }
        bfound = sel;
    }
    __syncthreads();
    if (t == 0) {
        int u = bfound;
        int cumBefore = (u == 0) ? 0 : csum[u - 1];
        int base2 = NBINS - (u + 1) * CH;
        int cum = cumBefore, bsel = base2;
        for (int b = base2 + CH - 1; b >= base2; b--) {
            cum += hist[(size_t)n * NBINS + b];
            if (cum >= KSEL) { bsel = b; break; }
        }
        thrbin[n] = bsel;
    }
}

__global__ void cand_kernel(const float* __restrict__ weight, const int* __restrict__ thrbin,
                            float* __restrict__ candw, int* __restrict__ cidx, int* __restrict__ ccnt) {
    int n = blockIdx.y;
    int i = blockIdx.x * 256 + threadIdx.x;
    if (i >= LPIX) return;
    float w = weight[(size_t)n * LPIX + i];
    int b = (int)(w * (float)NBINS);
    b = min(max(b, 0), NBINS - 1);
    if (b >= thrbin[n]) {
        int p = atomicAdd(&ccnt[n], 1);
        candw[(size_t)n * LPIX + p] = w;
        cidx[(size_t)n * LPIX + p] = i;
    }
}

__global__ __launch_bounds__(256) void rank_kernel(const float* __restrict__ candw, const int* __restrict__ cidx,
                                                   const int* __restrict__ ccnt,
                                                   float* __restrict__ conf, int* __restrict__ sidx) {
    int n = blockIdx.y, i = blockIdx.x;
    int cnt = ccnt[n];
    if (i >= cnt) return;
    float wi = candw[(size_t)n * LPIX + i];
    int ii = cidx[(size_t)n * LPIX + i];
    int r = 0;
    for (int j = threadIdx.x; j < cnt; j += 256) {
        float wj = candw[(size_t)n * LPIX + j];
        int ij = cidx[(size_t)n * LPIX + j];
        if (wj > wi || (wj == wi && ij < ii)) r++;
    }
    __shared__ int red[256];
    red[threadIdx.x] = r;
    __syncthreads();
    for (int s = 128; s > 0; s >>= 1) {
        if (threadIdx.x < s) red[threadIdx.x] += red[threadIdx.x + s];
        __syncthreads();
    }
    if (threadIdx.x == 0) {
        int rank = red[0];
        if (rank < KSEL) {
            sidx[(size_t)n * KSEL + rank] = ii;
            conf[(size_t)n * KSEL + rank] = wi;
        }
    }
}

// ---------------- gather selected tokens + bf16x3 splits + sq + inverse map ----------------
__global__ __launch_bounds__(256) void gather_src(const float* __restrict__ x, const int* __restrict__ sidx,
                                                  const float* __restrict__ conf,
                                                  float* __restrict__ src,
                                                  __bf16* __restrict__ sh, __bf16* __restrict__ sm,
                                                  __bf16* __restrict__ sl,
                                                  float* __restrict__ sq, int* __restrict__ inv) {
    int n = blockIdx.y, k = blockIdx.x, c = threadIdx.x;
    int idx = sidx[(size_t)n * KSEL + k];
    float cf = conf[(size_t)n * KSEL + k];
    float v = x[((size_t)n * CCH + c) * LPIX + idx] * cf;
    size_t o = ((size_t)n * KSEL + k) * CCH + c;
    src[o] = v;
    __bf16 h, m, l;
    split3(v, &h, &m, &l);
    sh[o] = h; sm[o] = m; sl[o] = l;
    __shared__ float red[256];
    red[c] = v * v;
    __syncthreads();
    for (int s = 128; s > 0; s >>= 1) {
        if (c < s) red[c] += red[c + s];
        __syncthreads();
    }
    if (c == 0) {
        sq[(size_t)n * KSEL + k] = red[0];
        inv[(size_t)n * LPIX + idx] = k;
    }
}

// ---------------- dist GEMM: MFMA bf16x3, triangular + mirror, XCD-swizzled tiles ----------------
__global__ __launch_bounds__(256) void dist_mfma(
    const __bf16* __restrict__ sh, const __bf16* __restrict__ sm, const __bf16* __restrict__ sl,
    const float* __restrict__ sq, float* __restrict__ dist, int n0) {
    int n = n0 + blockIdx.z;
    const size_t nbase = (size_t)n * KSEL * CCH;
    const float* sqn = sq + (size_t)n * KSEL;
    float* D = dist + (size_t)blockIdx.z * KSEL * KSEL;
    // bijective XCD swizzle over NT=406 tiles (q=50, r=6)
    int orig = blockIdx.x;
    int xcd = orig & 7, loc = orig >> 3;
    int b = (xcd < 6 ? xcd * 51 : 306 + (xcd - 6) * 50) + loc;
    int iT = (int)((sqrtf(8.f * (float)b + 1.f) - 1.f) * 0.5f);
    while ((iT + 1) * (iT + 2) / 2 <= b) iT++;
    while (iT * (iT + 1) / 2 > b) iT--;
    int jT = b - iT * (iT + 1) / 2;
    int bi = iT * 128, bj = jT * 128;
    __shared__ __align__(16) __bf16 As[3][128][40], Bs[3][128][40];
    int tid = threadIdx.x, w = tid >> 6, lane = tid & 63;
    int lrow = lane & 15, kg = lane >> 4;
    int wr = w >> 1, wc = w & 1;
    f32x4 acc[4][4];
#pragma unroll
    for (int i = 0; i < 4; i++)
#pragma unroll
        for (int j = 0; j < 4; j++) acc[i][j] = (f32x4){0.f, 0.f, 0.f, 0.f};

    int sr = tid & 127, g2 = tid >> 7;
    size_t ra = nbase + (size_t)min(bi + sr, KSEL - 1) * CCH;
    size_t rb = nbase + (size_t)min(bj + sr, KSEL - 1) * CCH;

    bf16x8 rA[3][2], rB[3][2];
#pragma unroll
    for (int s2 = 0; s2 < 2; s2++) {
        int cg = s2 * 2 + g2;
        rA[0][s2] = *(const bf16x8*)&sh[ra + cg * 8];
        rA[1][s2] = *(const bf16x8*)&sm[ra + cg * 8];
        rA[2][s2] = *(const bf16x8*)&sl[ra + cg * 8];
        rB[0][s2] = *(const bf16x8*)&sh[rb + cg * 8];
        rB[1][s2] = *(const bf16x8*)&sm[rb + cg * 8];
        rB[2][s2] = *(const bf16x8*)&sl[rb + cg * 8];
    }
    for (int c0 = 0; c0 < 256; c0 += 32) {
        __syncthreads();
#pragma unroll
        for (int s2 = 0; s2 < 2; s2++) {
            int cg = s2 * 2 + g2;
            *(bf16x8*)&As[0][sr][cg * 8] = rA[0][s2];
            *(bf16x8*)&As[1][sr][cg * 8] = rA[1][s2];
            *(bf16x8*)&As[2][sr][cg * 8] = rA[2][s2];
            *(bf16x8*)&Bs[0][sr][cg * 8] = rB[0][s2];
            *(bf16x8*)&Bs[1][sr][cg * 8] = rB[1][s2];
            *(bf16x8*)&Bs[2][sr][cg * 8] = rB[2][s2];
        }
        __syncthreads();
        if (c0 < 224) {
            int c1 = c0 + 32;
#pragma unroll
            for (int s2 = 0; s2 < 2; s2++) {
                int cg = s2 * 2 + g2;
                rA[0][s2] = *(const bf16x8*)&sh[ra + c1 + cg * 8];
                rA[1][s2] = *(const bf16x8*)&sm[ra + c1 + cg * 8];
                rA[2][s2] = *(const bf16x8*)&sl[ra + c1 + cg * 8];
                rB[0][s2] = *(const bf16x8*)&sh[rb + c1 + cg * 8];
                rB[1][s2] = *(const bf16x8*)&sm[rb + c1 + cg * 8];
                rB[2][s2] = *(const bf16x8*)&sl[rb + c1 + cg * 8];
            }
        }
        bf16x8 af[3][4], bf[3][4];
#pragma unroll
        for (int fj = 0; fj < 4; fj++) {
            int brow = wc * 64 + fj * 16 + lrow;
            bf[0][fj] = *(const bf16x8*)&Bs[0][brow][kg * 8];
            bf[1][fj] = *(const bf16x8*)&Bs[1][brow][kg * 8];
            bf[2][fj] = *(const bf16x8*)&Bs[2][brow][kg * 8];
        }
#pragma unroll
        for (int fi = 0; fi < 4; fi++) {
            int arow = wr * 64 + fi * 16 + lrow;
            af[0][fi] = *(const bf16x8*)&As[0][arow][kg * 8];
            af[1][fi] = *(const bf16x8*)&As[1][arow][kg * 8];
            af[2][fi] = *(const bf16x8*)&As[2][arow][kg * 8];
        }
#pragma unroll
        for (int t = 0; t < 6; t++) {
#pragma unroll
            for (int fi = 0; fi < 4; fi++) {
#pragma unroll
                for (int fj = 0; fj < 4; fj++) {
                    acc[fi][fj] = __builtin_amdgcn_mfma_f32_16x16x32_bf16(
                        af[SA6[t]][fi], bf[SB6[t]][fj], acc[fi][fj], 0, 0, 0);
                }
            }
        }
    }
#pragma unroll
    for (int fi = 0; fi < 4; fi++) {
        int gi0 = bi + wr * 64 + fi * 16;
        if (gi0 >= KSEL) continue;
        float4 siv = *(const float4*)&sqn[gi0 + kg * 4];
        float sia[4] = {siv.x, siv.y, siv.z, siv.w};
#pragma unroll
        for (int fj = 0; fj < 4; fj++) {
            int gj0 = bj + wc * 64 + fj * 16;
            if (gj0 >= KSEL) continue;
            int gj = gj0 + lrow;
            float sj = sqn[gj];
            float dv[4];
#pragma unroll
            for (int r = 0; r < 4; r++) {
                int gi = gi0 + kg * 4 + r;
                dv[r] = fmaxf(sia[r] + sj - 2.f * acc[fi][fj][r], 0.f);
                D[(size_t)gi * KSEL + gj] = dv[r];
            }
            if (iT != jT) {
                *(float4*)&D[(size_t)gj * KSEL + gi0 + kg * 4] = *(float4*)dv;
            }
        }
    }
}

// ---------------- density: 4 rows/block, 64 lanes/row, float4 + in-place LDS merge ----------------
__global__ __launch_bounds__(256) void knn_density(const float* __restrict__ dist, float* __restrict__ density, int n0) {
    int n = n0 + blockIdx.y;
    int row = threadIdx.x >> 6;
    int lane = threadIdx.x & 63;
    int i = blockIdx.x * 4 + row;
    const float4* row4 = (const float4*)(dist + (size_t)blockIdx.y * KSEL * KSEL + (size_t)i * KSEL);
    float tt[10];
#pragma unroll
    for (int r = 0; r < 10; r++) tt[r] = FMAXV;
    for (int j4 = lane; j4 < KSEL / 4; j4 += 64) {
        float4 v4 = row4[j4];
        float vv[4] = {v4.x, v4.y, v4.z, v4.w};
#pragma unroll
        for (int q = 0; q < 4; q++) {
            float v = vv[q];
            if (v < tt[9]) {
                tt[9] = v;
#pragma unroll
                for (int r = 9; r > 0; r--) {
                    if (tt[r] < tt[r - 1]) { float tmp = tt[r - 1]; tt[r - 1] = tt[r]; tt[r] = tmp; }
                }
            }
        }
    }
    __shared__ float ls[4][64][10];
#pragma unroll
    for (int r = 0; r < 10; r++) ls[row][lane][r] = tt[r];
    __syncthreads();
    for (int s = 32; s >= 1; s >>= 1) {
        if (lane < s) {
            float out[10];
            int ia = 0, ib = 0;
#pragma unroll
            for (int r = 0; r < 10; r++) {
                float va = ls[row][lane][ia], vb = ls[row][lane + s][ib];
                if (va <= vb) { out[r] = va; ia++; } else { out[r] = vb; ib++; }
            }
#pragma unroll
            for (int r = 0; r < 10; r++) ls[row][lane][r] = out[r];
        }
        __syncthreads();
    }
    if (lane == 0) {
        float sum = 0.f;
#pragma unroll
        for (int r = 0; r < 10; r++) sum += ls[row][0][r];
        density[(size_t)n * KSEL + i] = expf(-sum * 0.1f) + (float)i * 1e-6f;
    }
}

// ---------------- delta & score (marker token -> +inf score) ----------------
__global__ __launch_bounds__(256) void delta_score(const float* __restrict__ dist, const float* __restrict__ density,
                                                   float* __restrict__ scoreb, int n0) {
    int n = n0 + blockIdx.y;
    int i = blockIdx.x;
    const float4* row = (const float4*)(dist + (size_t)blockIdx.y * KSEL * KSEL + (size_t)i * KSEL);
    const float* dn = density + (size_t)n * KSEL;
    const float4* dn4 = (const float4*)dn;
    float di = dn[i];
    float mn = FMAXV;
    for (int j4 = threadIdx.x; j4 < KSEL / 4; j4 += 256) {
        float4 d = dn4[j4];
        float4 v = row[j4];
        if (d.x > di) mn = fminf(mn, v.x);
        if (d.y > di) mn = fminf(mn, v.y);
        if (d.z > di) mn = fminf(mn, v.z);
        if (d.w > di) mn = fminf(mn, v.w);
    }
    __shared__ float red[256];
    red[threadIdx.x] = mn;
    __syncthreads();
    for (int s = 128; s > 0; s >>= 1) {
        if (threadIdx.x < s) red[threadIdx.x] = fminf(red[threadIdx.x], red[threadIdx.x + s]);
        __syncthreads();
    }
    if (threadIdx.x == 0) {
        float d = red[0];
        scoreb[(size_t)n * KSEL + i] = (d == FMAXV) ? FMAXV : d * di;
    }
}

__global__ __launch_bounds__(256) void center_rank(const float* __restrict__ scoreb, int* __restrict__ centers,
                                                   int* __restrict__ crank, int n0) {
    int n = n0 + blockIdx.y;
    int i = blockIdx.x;
    const float* sc = scoreb + (size_t)n * KSEL;
    float si = sc[i];
    int r = 0;
    for (int j = threadIdx.x; j < KSEL; j += 256) {
        float sj = sc[j];
        if (sj > si || (sj == si && j < i)) r++;
    }
    __shared__ int red[256];
    red[threadIdx.x] = r;
    __syncthreads();
    for (int s = 128; s > 0; s >>= 1) {
        if (threadIdx.x < s) red[threadIdx.x] += red[threadIdx.x + s];
        __syncthreads();
    }
    if (threadIdx.x == 0) {
        int rank = red[0];
        if (rank < MCL) {
            centers[(size_t)n * MCL + rank] = i;
            crank[(size_t)n * KSEL + i] = rank;
        }
    }
}

// ---------------- assign + fused merge_w ----------------
__global__ __launch_bounds__(256) void assign_kernel(const float* __restrict__ dist, const int* __restrict__ centers,
                                                     const int* __restrict__ crank, const float* __restrict__ conf,
                                                     int* __restrict__ clus, float* __restrict__ allw, int n0) {
    int n = n0 + blockIdx.y;
    const float* D = dist + (size_t)blockIdx.y * KSEL * KSEL;
    int kl = threadIdx.x & 63, mc = threadIdx.x >> 6;
    int k = blockIdx.x * 64 + kl;
    const int* ctr = centers + (size_t)n * MCL;
    float mn = FMAXV;
    int am = MCL;
    for (int m = mc * 220; m < (mc + 1) * 220; m++) {
        float v = D[(size_t)ctr[m] * KSEL + k];
        if (v < mn) { mn = v; am = m; }
    }
    __shared__ float mv[4][64];
    __shared__ int mi[4][64];
    mv[mc][kl] = mn;
    mi[mc][kl] = am;
    __syncthreads();
    if (mc == 0) {
        float best = mv[0][kl];
        int bm = mi[0][kl];
#pragma unroll
        for (int c = 1; c < 4; c++) {
            float v = mv[c][kl];
            int im = mi[c][kl];
            if (v < best || (v == best && im < bm)) { best = v; bm = im; }
        }
        int cr = crank[(size_t)n * KSEL + k];
        int cl = (cr >= 0) ? cr : bm;
        clus[(size_t)n * KSEL + k] = cl;
        atomicAdd(&allw[(size_t)n * MCL + cl], conf[(size_t)n * KSEL + k]);
    }
}

__global__ void merge_feat(const float* __restrict__ src, const float* __restrict__ conf,
                           const int* __restrict__ clus, float* __restrict__ merged, int n0) {
    int n = n0 + blockIdx.y;
    int k = blockIdx.x, c = threadIdx.x;
    float v = src[((size_t)n * KSEL + k) * CCH + c] * conf[(size_t)n * KSEL + k];
    atomicAdd(&merged[((size_t)n * MCL + clus[(size_t)n * KSEL + k]) * CCH + c], v);
}

__global__ void merged_div(float* __restrict__ merged, const float* __restrict__ allw) {
    int nm = blockIdx.x, c = threadIdx.x;
    merged[(size_t)nm * CCH + c] /= (allw[nm] + 1e-6f);
}

// ---------------- bev + fused ego heads: one pass over x ----------------
__global__ __launch_bounds__(256) void bev_kernel(const float* __restrict__ x, const int* __restrict__ inv,
                                                  const int* __restrict__ clus, const float* __restrict__ merged,
                                                  const int* __restrict__ reclen, int B,
                                                  const float* __restrict__ clsw, const float* __restrict__ clsb,
                                                  const float* __restrict__ regw, const float* __restrict__ regb,
                                                  float* __restrict__ out, float* __restrict__ psm,
                                                  float* __restrict__ rm) {
    int n = blockIdx.y;
    int l0 = (blockIdx.x * 256 + threadIdx.x) * 4;
    bool ego = false;
    int bego = 0;
    {
        int off = 0;
        for (int b = 0; b < B; b++) {
            if (n == off) { ego = true; bego = b; break; }
            off += reclen[b];
        }
    }
    __shared__ float ws[16][256];
    __shared__ float bs[16];
    if (ego) {
        for (int i = threadIdx.x; i < 16 * 256; i += 256) {
            int o = i >> 8, c = i & 255;
            ws[o][c] = (o < 2) ? clsw[o * 256 + c] : regw[(o - 2) * 256 + c];
        }
        if (threadIdx.x < 16) bs[threadIdx.x] = (threadIdx.x < 2) ? clsb[threadIdx.x] : regb[threadIdx.x - 2];
        __syncthreads();
    }
    if (l0 >= LPIX) return;
    size_t base = (size_t)n * CCH * LPIX + l0;
    if (ego) {
        float acc[16][4] = {};
        for (int c = 0; c < CCH; c++) {
            float4 v = *(const float4*)&x[base + (size_t)c * LPIX];
            *(float4*)&out[base + (size_t)c * LPIX] = v;
#pragma unroll
            for (int o = 0; o < 16; o++) {
                float wv = ws[o][c];
                acc[o][0] += wv * v.x; acc[o][1] += wv * v.y; acc[o][2] += wv * v.z; acc[o][3] += wv * v.w;
            }
        }
#pragma unroll
        for (int o = 0; o < 2; o++) {
            float4 r;
            r.x = acc[o][0] + bs[o]; r.y = acc[o][1] + bs[o]; r.z = acc[o][2] + bs[o]; r.w = acc[o][3] + bs[o];
            *(float4*)&psm[((size_t)bego * 2 + o) * LPIX + l0] = r;
        }
#pragma unroll
        for (int o = 0; o < 14; o++) {
            float4 r;
            float bb = bs[o + 2];
            r.x = acc[o + 2][0] + bb; r.y = acc[o + 2][1] + bb; r.z = acc[o + 2][2] + bb; r.w = acc[o + 2][3] + bb;
            *(float4*)&rm[((size_t)bego * 14 + o) * LPIX + l0] = r;
        }
    } else {
        const float* mr0; const float* mr1; const float* mr2; const float* mr3;
        {
            int t0 = inv[(size_t)n * LPIX + l0 + 0];
            int t1 = inv[(size_t)n * LPIX + l0 + 1];
            int t2 = inv[(size_t)n * LPIX + l0 + 2];
            int t3 = inv[(size_t)n * LPIX + l0 + 3];
            mr0 = (t0 >= 0) ? merged + ((size_t)n * MCL + clus[(size_t)n * KSEL + t0]) * CCH : nullptr;
            mr1 = (t1 >= 0) ? merged + ((size_t)n * MCL + clus[(size_t)n * KSEL + t1]) * CCH : nullptr;
            mr2 = (t2 >= 0) ? merged + ((size_t)n * MCL + clus[(size_t)n * KSEL + t2]) * CCH : nullptr;
            mr3 = (t3 >= 0) ? merged + ((size_t)n * MCL + clus[(size_t)n * KSEL + t3]) * CCH : nullptr;
        }
        for (int c = 0; c < CCH; c++) {
            float4 v;
            v.x = mr0 ? mr0[c] : 0.f;
            v.y = mr1 ? mr1[c] : 0.f;
            v.z = mr2 ? mr2[c] : 0.f;
            v.w = mr3 ? mr3[c] : 0.f;
            *(float4*)&out[base + (size_t)c * LPIX] = v;
        }
    }
}

extern "C" void kernel_launch(void* const* d_in, const int* in_sizes, int n_in,
                              void* d_out, int out_size, void* d_ws, size_t ws_size,
                              hipStream_t stream) {
    const float* x    = (const float*)d_in[0];
    const float* prio = (const float*)d_in[1];
    const float* w1   = (const float*)d_in[2];
    const float* b1   = (const float*)d_in[3];
    const float* w2   = (const float*)d_in[4];
    const float* b2   = (const float*)d_in[5];
    const float* clsw = (const float*)d_in[6];
    const float* clsb = (const float*)d_in[7];
    const float* regw = (const float*)d_in[8];
    const float* regb = (const float*)d_in[9];
    const int* reclen = (const int*)d_in[10];
    int N = in_sizes[0] / (CCH * LPIX);
    int B = in_sizes[10];
    float* out = (float*)d_out;

    char* p = (char*)d_ws;
    size_t off = 0;
    auto alloc = [&](size_t bytes) -> void* {
        void* r = p + off;
        off += (bytes + 255) & ~(size_t)255;
        return r;
    };
    __bf16* w1h    = (__bf16*)alloc(256 * 256 * 2);
    __bf16* w1m    = (__bf16*)alloc(256 * 256 * 2);
    __bf16* w1l    = (__bf16*)alloc(256 * 256 * 2);
    float* weight  = (float*)alloc((size_t)N * LPIX * 4);
    int*   hist    = (int*)alloc((size_t)N * NBINS * 4);
    int*   thrbin  = (int*)alloc((size_t)N * 4);
    int*   ccnt    = (int*)alloc((size_t)N * 4);
    float* candw   = (float*)alloc((size_t)N * LPIX * 4);
    int*   cidx    = (int*)alloc((size_t)N * LPIX * 4);
    int*   sidx    = (int*)alloc((size_t)N * KSEL * 4);
    float* conf    = (float*)alloc((size_t)N * KSEL * 4);
    float* src     = (float*)alloc((size_t)N * KSEL * CCH * 4);
    __bf16* srch   = (__bf16*)alloc((size_t)N * KSEL * CCH * 2);
    __bf16* srcm   = (__bf16*)alloc((size_t)N * KSEL * CCH * 2);
    __bf16* srcl   = (__bf16*)alloc((size_t)N * KSEL * CCH * 2);
    float* sq      = (float*)alloc((size_t)N * KSEL * 4);
    int*   inv     = (int*)alloc((size_t)N * LPIX * 4);
    float* density = (float*)alloc((size_t)N * KSEL * 4);
    float* scoreb  = (float*)alloc((size_t)N * KSEL * 4);
    int*   centers = (int*)alloc((size_t)N * MCL * 4);
    int*   crank   = (int*)alloc((size_t)N * KSEL * 4);
    int*   clus    = (int*)alloc((size_t)N * KSEL * 4);
    float* allw    = (float*)alloc((size_t)N * MCL * 4);
    float* merged  = (float*)alloc((size_t)N * MCL * CCH * 4);
    const size_t distB = (size_t)KSEL * KSEL * 4;
    size_t rem = (ws_size > off) ? (ws_size - off) : 0;
    int nd = (int)(rem / distB);
    if (nd < 1) nd = 1;
    if (nd > N) nd = N;
    float* dist = (float*)alloc(distB * nd);

    hipMemsetAsync(hist, 0, (size_t)N * NBINS * 4, stream);
    hipMemsetAsync(ccnt, 0, (size_t)N * 4, stream);
    hipMemsetAsync(inv, 0xFF, (size_t)N * LPIX * 4, stream);
    hipMemsetAsync(crank, 0xFF, (size_t)N * KSEL * 4, stream);
    hipMemsetAsync(allw, 0, (size_t)N * MCL * 4, stream);
    hipMemsetAsync(merged, 0, (size_t)N * MCL * CCH * 4, stream);

    split_w1<<<256, 256, 0, stream>>>(w1, w1h, w1m, w1l);
    score_mfma<<<dim3(LPIX / 64, N), 256, 0, stream>>>(x, prio, w1h, w1m, w1l, b1, w2, b2, weight, hist);
    thr_kernel<<<N, 256, 0, stream>>>(hist, thrbin);
    cand_kernel<<<dim3((LPIX + 255) / 256, N), 256, 0, stream>>>(weight, thrbin, candw, cidx, ccnt);
    rank_kernel<<<dim3(8192, N), 256, 0, stream>>>(candw, cidx, ccnt, conf, sidx);
    gather_src<<<dim3(KSEL, N), 256, 0, stream>>>(x, sidx, conf, src, srch, srcm, srcl, sq, inv);

    const int TI = (KSEL + 127) / 128;           // 28
    const int NT = TI * (TI + 1) / 2;            // 406 lower-triangle tiles
    for (int g = 0; g < N; g += nd) {
        int nb = (N - g < nd) ? (N - g) : nd;
        dist_mfma<<<dim3(NT, 1, nb), 256, 0, stream>>>(srch, srcm, srcl, sq, dist, g);
        knn_density<<<dim3(KSEL / 4, nb), 256, 0, stream>>>(dist, density, g);
        delta_score<<<dim3(KSEL, nb), 256, 0, stream>>>(dist, density, scoreb, g);
        center_rank<<<dim3(KSEL, nb), 256, 0, stream>>>(scoreb, centers, crank, g);
        assign_kernel<<<dim3(KSEL / 64, nb), 256, 0, stream>>>(dist, centers, crank, conf, clus, allw, g);
        merge_feat<<<dim3(KSEL, nb), 256, 0, stream>>>(src, conf, clus, merged, g);
    }
    merged_div<<<N * MCL, 256, 0, stream>>>(merged, allw);

    float* psm = out + (size_t)N * CCH * LPIX;
    float* rm  = psm + (size_t)B * 2 * LPIX;
    bev_kernel<<<dim3((LPIX / 4 + 255) / 256, N), 256, 0, stream>>>(
        x, inv, clus, merged, reclen, B, clsw, clsb, regw, regb, out, psm, rm);
}